// Round 7
// baseline (886.773 us; speedup 1.0000x reference)
//
#include <hip/hip_runtime.h>
#include <math.h>
#include <stdint.h>

// Problem dims (fixed by reference)
static constexpr int Bb  = 4;
static constexpr int Ll  = 4096;
static constexpr int Dd  = 1024;
static constexpr int DFF = 4096;
static constexpr int Mm  = Bb * Ll;     // 16384 rows
static constexpr int CH  = 64;          // scan chunks
static constexpr int CS  = Ll / CH;     // 64 steps per chunk
static constexpr float EPS = 1e-6f;

typedef __attribute__((ext_vector_type(8))) short short8;     // 8 bf16 (4 VGPRs)
typedef __attribute__((ext_vector_type(4))) float floatx4;    // MFMA C/D
typedef __attribute__((ext_vector_type(4))) unsigned short us4;

__device__ __forceinline__ float sigmoidf_(float v) { return 1.0f / (1.0f + __expf(-v)); }
// safe at +-inf: 2*sigmoid(2x)-1
__device__ __forceinline__ float fast_tanh(float x) {
    return 2.0f / (1.0f + __expf(-2.0f * x)) - 1.0f;
}
__device__ __forceinline__ ushort f2bf(float f) {
    union { float f; uint32_t u; } v; v.f = f;
    return (ushort)((v.u + 0x7FFFu + ((v.u >> 16) & 1u)) >> 16);   // RNE
}
__device__ __forceinline__ float bf2f(ushort h) {
    union { uint32_t u; float f; } v; v.u = (uint32_t)h << 16; return v.f;
}

// async global->LDS, 16 bytes per lane (wave-uniform base + lane*16 layout)
__device__ __forceinline__ void gload16(const ushort* g, ushort* l) {
    __builtin_amdgcn_global_load_lds(
        (const __attribute__((address_space(1))) uint32_t*)g,
        (__attribute__((address_space(3))) uint32_t*)l, 16, 0, 0);
}

// ===========================================================================
// 2-phase pipelined dual-GEMM core, 512 thr / 8 waves, BK=64.  (R6 base.)
//   Four schedule variants (R1/R2/R3/R6) all measured 39-42% MfmaUtil —
//   intra-block schedule lever exhausted.  R7 micro-change only: fragment
//   read ORDER — issue a0,b0,c0,b1,c1 FIRST so MFMA #1-4's operands return
//   early (first-MFMA dead-start ~860 -> ~300 cyc); a1..a7 follow and hide
//   under MFMAs via compiler lgkmcnt.  Everything else unchanged.
//   Counted-vmcnt ledger (never 0 mid-loop): prologue stages tile0 (8),
//   vmcnt(4) -> kk0 landed, 4 in flight.  Loop ph0: +8 (tile t+1),
//   vmcnt(8) retires {A1,B1(t)} for ph1.  ph1: vmcnt(4) retires
//   {A0,B0(t+1)} for next ph0.  Epilogue: vmcnt(0) drains.
//   Race-safety: each wave's ds_reads complete before its own MFMAs
//   (compiler lgkm waits) hence before its barrier arrival; writes into a
//   buffer issue only after the barrier that all readers passed.
//   Swizzle (0-conflict proven): chunk (m,s) holds k-block s ^ ((m>>1)&3);
//   read slot = q ^ ((fr>>1)&3).
// ===========================================================================
static constexpr int HT_US  = 256 * 32;       // ushorts per half-tile (16 KB)
static constexpr int BUF_US = 4 * HT_US;      // per buffer (64 KB)

__device__ __forceinline__ void gemm_core_2ph(
    const ushort* __restrict__ A, const ushort* __restrict__ B1,
    const ushort* __restrict__ B2, int m0, int n0b1, int n0b2, int K,
    ushort* lds, floatx4 (&acc1)[8][2], floatx4 (&acc2)[8][2])
{
    const int tid = threadIdx.x;
    const int mm = tid >> 2, ss = tid & 3;
    const int kb = ss ^ ((mm >> 1) & 3);          // swizzled k-slot (staging)
    const ushort* pA0 = A  + (size_t)(m0 + mm) * K + kb * 8;
    const ushort* pA1 = pA0 + (size_t)128 * K;
    const ushort* pB0 = B1 + (size_t)(n0b1 + mm) * K + kb * 8;
    const ushort* pB1 = B2 + (size_t)(n0b2 + mm) * K + kb * 8;

    const int wave = tid >> 6, lane = tid & 63;
    const int wr = wave >> 2, wc = wave & 3;      // 2M x 4N wave grid
    const int fr = lane & 15, q = lane >> 4;
    const int slot8 = (q ^ ((fr >> 1) & 3)) << 3;
    const int aoff  = (wr * 128 + fr) * 32 + slot8;             // + mi*512
    const int boff  = 2 * HT_US + (wc * 32 + fr) * 32 + slot8;  // + ni*512 (+4096 side2)

    const int NT = K >> 6;

    // Issue order: {A0,B0} (4 loads) then {A1,B1} (4) -> vmcnt groups of 4.
#define STG_TILE(bsel, tt) do { \
        ushort* dA0 = lds + (bsel) * BUF_US; \
        ushort* dA1 = dA0 + HT_US; \
        ushort* dB0 = dA0 + 2 * HT_US; \
        ushort* dB1 = dA0 + 3 * HT_US; \
        int o0 = (tt) * 64, o1 = o0 + 32; \
        gload16(pA0 + o0, dA0 + tid * 8); gload16(pA1 + o0, dA0 + (tid + 512) * 8); \
        gload16(pB0 + o0, dB0 + tid * 8); gload16(pB1 + o0, dB0 + (tid + 512) * 8); \
        gload16(pA0 + o1, dA1 + tid * 8); gload16(pA1 + o1, dA1 + (tid + 512) * 8); \
        gload16(pB0 + o1, dB1 + tid * 8); gload16(pB1 + o1, dB1 + (tid + 512) * 8); } while (0)

    // HEAD: operands of the first MFMAs (a0,b0,c0,b1,c1) issue first.
#define READ_HEAD(base) do { \
        a[0] = *(const short8*)&(base)[aoff]; \
        b[0] = *(const short8*)&(base)[boff]; \
        c[0] = *(const short8*)&(base)[boff + 4096]; \
        b[1] = *(const short8*)&(base)[boff + 512]; \
        c[1] = *(const short8*)&(base)[boff + 4096 + 512]; } while (0)
#define READ_TAIL(base) do { \
        _Pragma("unroll") \
        for (int i_ = 1; i_ < 8; ++i_) a[i_] = *(const short8*)&(base)[aoff + i_ * 512]; } while (0)

#define MFMA_FULL() do { \
        __builtin_amdgcn_s_setprio(1); \
        _Pragma("unroll") \
        for (int mi_ = 0; mi_ < 8; ++mi_) { \
            acc1[mi_][0] = __builtin_amdgcn_mfma_f32_16x16x32_bf16(a[mi_], b[0], acc1[mi_][0], 0, 0, 0); \
            acc2[mi_][0] = __builtin_amdgcn_mfma_f32_16x16x32_bf16(a[mi_], c[0], acc2[mi_][0], 0, 0, 0); \
            acc1[mi_][1] = __builtin_amdgcn_mfma_f32_16x16x32_bf16(a[mi_], b[1], acc1[mi_][1], 0, 0, 0); \
            acc2[mi_][1] = __builtin_amdgcn_mfma_f32_16x16x32_bf16(a[mi_], c[1], acc2[mi_][1], 0, 0, 0); \
        } \
        __builtin_amdgcn_s_setprio(0); } while (0)

    // ---- prologue: stage K-tile 0; keep its kk1 halves in flight ----
    STG_TILE(0, 0);
    asm volatile("s_waitcnt vmcnt(4)" ::: "memory");
    __builtin_amdgcn_s_barrier();

    int t = 0;
    for (; t < NT - 1; ++t) {
        const int buf = t & 1, nbuf = buf ^ 1;
        const ushort* Ab = lds + buf * BUF_US;
        short8 a[8], b[2], c[2];

        // ---------- phase 0: kk0 (12 ds_read + stage tile t+1 + 32 MFMA) ----
        READ_HEAD(Ab);
        STG_TILE(nbuf, t + 1);
        READ_TAIL(Ab);
        MFMA_FULL();
        asm volatile("s_waitcnt vmcnt(8)" ::: "memory");
        __builtin_amdgcn_s_barrier();

        // ---------- phase 1: kk1 (12 ds_read + 32 MFMA) ----------
        const ushort* Ab1 = Ab + HT_US;
        READ_HEAD(Ab1);
        READ_TAIL(Ab1);
        MFMA_FULL();
        asm volatile("s_waitcnt vmcnt(4)" ::: "memory");
        __builtin_amdgcn_s_barrier();
    }
    // ---- epilogue: last K-tile (no prefetch) ----
    {
        const int buf = t & 1;
        const ushort* Ab = lds + buf * BUF_US;
        short8 a[8], b[2], c[2];
        READ_HEAD(Ab);
        READ_TAIL(Ab);
        MFMA_FULL();
        asm volatile("s_waitcnt vmcnt(0)" ::: "memory");
        __builtin_amdgcn_s_barrier();
        const ushort* Ab1 = Ab + HT_US;
        READ_HEAD(Ab1);
        READ_TAIL(Ab1);
        MFMA_FULL();
    }
#undef STG_TILE
#undef READ_HEAD
#undef READ_TAIL
#undef MFMA_FULL
}

// ---------------------------------------------------------------------------
// Fused QuasiLSTM gate GEMM (dual, shared A), N = 2048:
//   W1t rows [0,1024) = w_input^T,  [1024,2048) = w_forget^T
//   W2t rows [0,1024) = w_igate^T,  [1024,2048) = w_ogate^T
// col <  1024:  Gb  = tanh(z1) * sigmoid(z2)
// col >= 1024:  Ga  = sigmoid(z1);  Gog = sigmoid(z2)
// ---------------------------------------------------------------------------
__global__ __launch_bounds__(512) void mfma_gemm_gates(
    const ushort* __restrict__ A, const ushort* __restrict__ W1t,
    const ushort* __restrict__ W2t,
    const float* __restrict__ b_input, const float* __restrict__ b_forget,
    const float* __restrict__ b_igate, const float* __restrict__ b_ogate,
    ushort* __restrict__ Ga, ushort* __restrict__ Gb, ushort* __restrict__ Gog)
{
    __shared__ __align__(16) ushort lds[2 * BUF_US];
    // XCD-slice swizzle: each XCD owns 2 bx columns (B-slice 1MB, L2-resident)
    int xcd = blockIdx.x & 7, i = blockIdx.x >> 3;   // i in [0,128)
    int bx = xcd * 2 + (i & 1), by = i >> 1;
    int m0 = by * 256, n0 = bx * 128;

    floatx4 acc1[8][2] = {};
    floatx4 acc2[8][2] = {};
    gemm_core_2ph(A, W1t, W2t, m0, n0, n0, Dd, lds, acc1, acc2);

    int tid = threadIdx.x, wave = tid >> 6, lane = tid & 63;
    int wr = wave >> 2, wc = wave & 3, fr = lane & 15, q = lane >> 4;
    #pragma unroll
    for (int ni = 0; ni < 2; ++ni) {
        int col = n0 + wc * 32 + ni * 16 + fr;        // [0,2048)
        if (col < 1024) {
            float b1v = b_input[col], b2v = b_igate[col];
            #pragma unroll
            for (int mi = 0; mi < 8; ++mi)
                #pragma unroll
                for (int r = 0; r < 4; ++r) {
                    int row = m0 + wr * 128 + mi * 16 + q * 4 + r;
                    float z1 = acc1[mi][ni][r] + b1v;
                    float z2 = acc2[mi][ni][r] + b2v;
                    Gb[(size_t)row * Dd + col] = f2bf(fast_tanh(z1) * sigmoidf_(z2));
                }
        } else {
            int c2 = col - 1024;
            float b1v = b_forget[c2], b2v = b_ogate[c2];
            #pragma unroll
            for (int mi = 0; mi < 8; ++mi)
                #pragma unroll
                for (int r = 0; r < 4; ++r) {
                    int row = m0 + wr * 128 + mi * 16 + q * 4 + r;
                    float z1 = acc1[mi][ni][r] + b1v;
                    float z2 = acc2[mi][ni][r] + b2v;
                    Ga[(size_t)row * Dd + c2]  = f2bf(sigmoidf_(z1));
                    Gog[(size_t)row * Dd + c2] = f2bf(sigmoidf_(z2));
                }
        }
    }
}

// ---------------------------------------------------------------------------
// MFMA dual GEMM for SwiGLU: C = (A@W1+b1) * silu(A@W2+b2), bf16 out
// ---------------------------------------------------------------------------
__global__ __launch_bounds__(512) void mfma_gemm_swiglu(
    const ushort* __restrict__ A, const ushort* __restrict__ W1t,
    const float* __restrict__ b1, const ushort* __restrict__ W2t,
    const float* __restrict__ b2, ushort* __restrict__ C)
{
    __shared__ __align__(16) ushort lds[2 * BUF_US];
    // XCD-slice swizzle: each XCD owns 4 bx columns (B-slice 2MB, L2-resident)
    int xcd = blockIdx.x & 7, i = blockIdx.x >> 3;   // i in [0,256)
    int bx = xcd * 4 + (i & 3), by = i >> 2;
    int m0 = by * 256, n0 = bx * 128;

    floatx4 acc1[8][2] = {};
    floatx4 acc2[8][2] = {};
    gemm_core_2ph(A, W1t, W2t, m0, n0, n0, Dd, lds, acc1, acc2);

    int tid = threadIdx.x, wave = tid >> 6, lane = tid & 63;
    int wr = wave >> 2, wc = wave & 3, fr = lane & 15, q = lane >> 4;
    #pragma unroll
    for (int ni = 0; ni < 2; ++ni) {
        int col = n0 + wc * 32 + ni * 16 + fr;
        float b1v = b1[col], b2v = b2[col];
        #pragma unroll
        for (int mi = 0; mi < 8; ++mi)
            #pragma unroll
            for (int r = 0; r < 4; ++r) {
                int row = m0 + wr * 128 + mi * 16 + q * 4 + r;
                float z1 = acc1[mi][ni][r] + b1v;
                float z2 = acc2[mi][ni][r] + b2v;
                C[(size_t)row * DFF + col] = f2bf(z1 * z2 * sigmoidf_(z2));
            }
    }
}

// ---------------------------------------------------------------------------
// MFMA residual GEMM: out_f32 = A_bf16[M,K] @ Wt[N,K]^T + bias + R (R == out)
// Single-B: the 256-wide N tile is two 128 halves (acc1/acc2).
// ---------------------------------------------------------------------------
__global__ __launch_bounds__(512) void mfma_gemm_residual(
    const ushort* __restrict__ A, const ushort* __restrict__ Wt,
    const float* __restrict__ bias, float* __restrict__ C)
{
    __shared__ __align__(16) ushort lds[2 * BUF_US];
    int xcd = blockIdx.x & 7, i = blockIdx.x >> 3;   // i in [0,32)
    int s = xcd * 32 + i;
    int bx = s & 3, by = s >> 2;                     // bx fast: A-panel reuse
    int m0 = by * 256, n0 = bx * 256;

    floatx4 acc1[8][2] = {};
    floatx4 acc2[8][2] = {};
    gemm_core_2ph(A, Wt, Wt, m0, n0, n0 + 128, DFF, lds, acc1, acc2);

    int tid = threadIdx.x, wave = tid >> 6, lane = tid & 63;
    int wr = wave >> 2, wc = wave & 3, fr = lane & 15, q = lane >> 4;
    #pragma unroll
    for (int ni = 0; ni < 2; ++ni) {
        int col1 = n0 + wc * 32 + ni * 16 + fr;
        int col2 = col1 + 128;
        float bs1 = bias[col1], bs2 = bias[col2];
        #pragma unroll
        for (int mi = 0; mi < 8; ++mi)
            #pragma unroll
            for (int r = 0; r < 4; ++r) {
                int row = m0 + wr * 128 + mi * 16 + q * 4 + r;
                size_t i1 = (size_t)row * Dd + col1;
                size_t i2 = (size_t)row * Dd + col2;
                C[i1] = acc1[mi][ni][r] + bs1 + C[i1];  // same-thread RMW
                C[i2] = acc2[mi][ni][r] + bs2 + C[i2];
            }
    }
}

// ---------------------------------------------------------------------------
// Weight cast+transpose: W fp32 [K,N] -> Wt bf16 [N,K]
// ---------------------------------------------------------------------------
__global__ __launch_bounds__(256) void transpose_cast_kernel(
    const float* __restrict__ W, ushort* __restrict__ Wt, int K, int N)
{
    __shared__ float t[32][33];
    int lx = threadIdx.x & 31, ly = threadIdx.x >> 5;   // 32 x 8
    int n = blockIdx.x * 32 + lx;
    #pragma unroll
    for (int i = 0; i < 4; ++i) {
        int k = blockIdx.y * 32 + ly + i * 8;
        t[ly + i * 8][lx] = W[(size_t)k * N + n];
    }
    __syncthreads();
    int k2 = blockIdx.y * 32 + lx;
    #pragma unroll
    for (int i = 0; i < 4; ++i) {
        int n2 = blockIdx.x * 32 + ly + i * 8;
        Wt[(size_t)n2 * K + k2] = f2bf(t[lx][ly + i * 8]);
    }
}

// Batched version for the four 1024x1024 gate weights (grid.z picks source).
__global__ __launch_bounds__(256) void transpose_cast_gates(
    const float* __restrict__ w_i, const float* __restrict__ w_f,
    const float* __restrict__ w_g, const float* __restrict__ w_o,
    ushort* __restrict__ W1t, ushort* __restrict__ W2t)
{
    int z = blockIdx.z;
    const float* W = (z == 0) ? w_i : (z == 1) ? w_f : (z == 2) ? w_g : w_o;
    ushort* Wt = (z == 0) ? W1t : (z == 1) ? W1t + (size_t)1024 * Dd
               : (z == 2) ? W2t : W2t + (size_t)1024 * Dd;
    __shared__ float t[32][33];
    int lx = threadIdx.x & 31, ly = threadIdx.x >> 5;
    int n = blockIdx.x * 32 + lx;
    #pragma unroll
    for (int i = 0; i < 4; ++i) {
        int k = blockIdx.y * 32 + ly + i * 8;
        t[ly + i * 8][lx] = W[(size_t)k * Dd + n];
    }
    __syncthreads();
    int k2 = blockIdx.y * 32 + lx;
    #pragma unroll
    for (int i = 0; i < 4; ++i) {
        int n2 = blockIdx.x * 32 + ly + i * 8;
        Wt[(size_t)n2 * Dd + k2] = f2bf(t[lx][ly + i * 8]);
    }
}

// ---------------------------------------------------------------------------
// RMSNorm fp32 in -> bf16 out.  One WAVE per row (4 rows/block):
// pure shfl_xor reduce — no LDS, no __syncthreads.
// ---------------------------------------------------------------------------
__global__ __launch_bounds__(256) void rmsnorm_bf16_kernel(
    const float* __restrict__ x, const float* __restrict__ w,
    ushort* __restrict__ o)
{
    int wave = threadIdx.x >> 6, lane = threadIdx.x & 63;
    int row = blockIdx.x * 4 + wave;
    const float4* xr = (const float4*)(x + (size_t)row * Dd);
    float4 v[4];
    float ss = 0.f;
    #pragma unroll
    for (int j = 0; j < 4; ++j) {
        v[j] = xr[lane + j * 64];
        ss += v[j].x * v[j].x + v[j].y * v[j].y + v[j].z * v[j].z + v[j].w * v[j].w;
    }
    #pragma unroll
    for (int off = 1; off < 64; off <<= 1) ss += __shfl_xor(ss, off, 64);
    float scale = rsqrtf(ss * (1.0f / Dd) + EPS);
    #pragma unroll
    for (int j = 0; j < 4; ++j) {
        float4 wv = ((const float4*)w)[lane + j * 64];
        us4 ov;
        ov.x = f2bf(v[j].x * scale * wv.x);
        ov.y = f2bf(v[j].y * scale * wv.y);
        ov.z = f2bf(v[j].z * scale * wv.z);
        ov.w = f2bf(v[j].w * scale * wv.w);
        *(us4*)&o[(size_t)row * Dd + (lane + j * 64) * 4] = ov;
    }
}

// ---------------------------------------------------------------------------
// Chunked linear recurrence, 4 channels/thread (ushort4 loads)
// ---------------------------------------------------------------------------
__global__ __launch_bounds__(256) void scan_pass1(
    const ushort* __restrict__ Ga, const ushort* __restrict__ Gb,
    float* __restrict__ P, float* __restrict__ Hend)
{
    int tid = threadIdx.x;
    int c = blockIdx.x, b = blockIdx.y;
    size_t base = ((size_t)b * Ll + (size_t)c * CS) * Dd + tid * 4;
    float p[4] = {1.f, 1.f, 1.f, 1.f};
    float h[4] = {};
    #pragma unroll 4
    for (int t = 0; t < CS; ++t) {
        us4 av = *(const us4*)&Ga[base + (size_t)t * Dd];
        us4 bv = *(const us4*)&Gb[base + (size_t)t * Dd];
        #pragma unroll
        for (int j = 0; j < 4; ++j) {
            float aa = bf2f(av[j]);
            float bb = bf2f(bv[j]);
            p[j] *= aa;
            h[j] = aa * h[j] + bb;
        }
    }
    size_t o = ((size_t)b * CH + c) * Dd + tid * 4;
    *(float4*)&P[o]    = make_float4(p[0], p[1], p[2], p[3]);
    *(float4*)&Hend[o] = make_float4(h[0], h[1], h[2], h[3]);
}

// 64-thread blocks: spread the 4096 serial carry chains over 64 CUs
// (was 16 blocks -> only 16 CUs hiding the dependent-load latency).
__global__ __launch_bounds__(64) void scan_pass2(
    const float* __restrict__ P, const float* __restrict__ Hend,
    const float* __restrict__ h0, float* __restrict__ Carry)
{
    int idx = blockIdx.x * 64 + threadIdx.x;  // B*D = 4096
    int b = idx / Dd, d = idx % Dd;
    float carry = h0[d];
    for (int c = 0; c < CH; ++c) {
        size_t o = ((size_t)b * CH + c) * Dd + d;
        Carry[o] = carry;
        carry = P[o] * carry + Hend[o];
    }
}

// Replay with carry + fused ogate/residual + fused RMSNorm2.
// 512 threads / 2 chunks per block; software-pipelined reduction:
// ONE __syncthreads per step (read red[t&1], pre-write red[(t+1)&1]).
// Race-free: red[p] is read at iter t (after the sync ending iter t-1)
// and next written at iter t+1 (after the sync ending iter t).
__global__ __launch_bounds__(512) void scan_pass3_norm(
    const ushort* __restrict__ Ga, const ushort* __restrict__ Gb,
    const ushort* __restrict__ Gog, const float* __restrict__ Carry,
    const float* __restrict__ x, const float* __restrict__ norm2w,
    float* __restrict__ x1, ushort* __restrict__ xnb)
{
    int tid = threadIdx.x;
    int half = tid >> 8, ltid = tid & 255;
    int c = blockIdx.x * 2 + half, b = blockIdx.y;
    size_t base = ((size_t)b * Ll + (size_t)c * CS) * Dd + ltid * 4;
    float4 h4 = *(const float4*)&Carry[((size_t)b * CH + c) * Dd + ltid * 4];
    float h[4] = {h4.x, h4.y, h4.z, h4.w};
    float4 w4 = ((const float4*)norm2w)[ltid];
    float wv[4] = {w4.x, w4.y, w4.z, w4.w};
    __shared__ float red[2][2][4];    // [parity][half][wave-of-half]

    float v[4];
    // ---- prologue: step 0 ----
    {
        us4 av = *(const us4*)&Ga[base];
        us4 bv = *(const us4*)&Gb[base];
        us4 gv = *(const us4*)&Gog[base];
        float4 xv = *(const float4*)&x[base];
        float xs[4] = {xv.x, xv.y, xv.z, xv.w};
        #pragma unroll
        for (int j = 0; j < 4; ++j) {
            float aa = bf2f(av[j]);
            float bb = bf2f(bv[j]);
            h[j] = aa * h[j] + bb;
            v[j] = fast_tanh(h[j]) * bf2f(gv[j]) + xs[j];
        }
        *(float4*)&x1[base] = make_float4(v[0], v[1], v[2], v[3]);
        float ss = v[0]*v[0] + v[1]*v[1] + v[2]*v[2] + v[3]*v[3];
        #pragma unroll
        for (int off = 32; off > 0; off >>= 1) ss += __shfl_down(ss, off, 64);
        if ((ltid & 63) == 0) red[0][half][ltid >> 6] = ss;
    }
    __syncthreads();

    for (int t = 0; t < CS; ++t) {
        int p = t & 1;
        float scale = rsqrtf((red[p][half][0] + red[p][half][1] +
                              red[p][half][2] + red[p][half][3]) * (1.0f / Dd) + EPS);
        us4 ov;
        #pragma unroll
        for (int j = 0; j < 4; ++j) ov[j] = f2bf(v[j] * scale * wv[j]);
        *(us4*)&xnb[base + (size_t)t * Dd] = ov;

        if (t + 1 < CS) {
            size_t i = base + (size_t)(t + 1) * Dd;
            us4 av = *(const us4*)&Ga[i];
            us4 bv = *(const us4*)&Gb[i];
            us4 gv = *(const us4*)&Gog[i];
            float4 xv = *(const float4*)&x[i];
            float xs[4] = {xv.x, xv.y, xv.z, xv.w};
            #pragma unroll
            for (int j = 0; j < 4; ++j) {
                float aa = bf2f(av[j]);
                float bb = bf2f(bv[j]);
                h[j] = aa * h[j] + bb;
                v[j] = fast_tanh(h[j]) * bf2f(gv[j]) + xs[j];
            }
            *(float4*)&x1[i] = make_float4(v[0], v[1], v[2], v[3]);
            float ss = v[0]*v[0] + v[1]*v[1] + v[2]*v[2] + v[3]*v[3];
            #pragma unroll
            for (int off = 32; off > 0; off >>= 1) ss += __shfl_down(ss, off, 64);
            if ((ltid & 63) == 0) red[(t + 1) & 1][half][ltid >> 6] = ss;
        }
        __syncthreads();
    }
}

// ---------------------------------------------------------------------------
// Launch. Workspace (195 MB):
//   [0,4)   MB: W1t gates bf16 [2048,1024]   (input | forget)
//   [4,8)   MB: W2t gates bf16 [2048,1024]   (igate | ogate)
//   [8,16)  MB: wtFC   [16,24) MB: wtFCA   [24,32) MB: wtOUT
//   [32,64) MB: xnb bf16 [M,1024]
//   [64,192)MB: Ga/Gb/Gog bf16 (32MB each) -> later hff bf16 [M,4096]
//   [192,195)MB: P, Hend, Carry fp32
// d_out doubles as x1 then final out.
// ---------------------------------------------------------------------------
extern "C" void kernel_launch(void* const* d_in, const int* in_sizes, int n_in,
                              void* d_out, int out_size, void* d_ws, size_t ws_size,
                              hipStream_t stream)
{
    const float* x        = (const float*)d_in[0];
    const float* w_forget = (const float*)d_in[1];
    const float* b_forget = (const float*)d_in[2];
    const float* w_input  = (const float*)d_in[3];
    const float* b_input  = (const float*)d_in[4];
    const float* w_igate  = (const float*)d_in[5];
    const float* b_igate  = (const float*)d_in[6];
    const float* w_ogate  = (const float*)d_in[7];
    const float* b_ogate  = (const float*)d_in[8];
    const float* h0       = (const float*)d_in[9];
    const float* norm1_w  = (const float*)d_in[10];
    const float* norm2_w  = (const float*)d_in[11];
    const float* w_fc     = (const float*)d_in[12];
    const float* b_fc     = (const float*)d_in[13];
    const float* w_fc_act = (const float*)d_in[14];
    const float* b_fc_act = (const float*)d_in[15];
    const float* w_out    = (const float*)d_in[16];
    const float* b_out    = (const float*)d_in[17];
    float* out = (float*)d_out;   // x1, then final out

    char* ws = (char*)d_ws;
    const size_t MB = 1ull << 20;
    ushort* wtG1  = (ushort*)(ws + 0 * MB);
    ushort* wtG2  = (ushort*)(ws + 4 * MB);
    ushort* wtFC  = (ushort*)(ws + 8 * MB);
    ushort* wtFCA = (ushort*)(ws + 16 * MB);
    ushort* wtOUT = (ushort*)(ws + 24 * MB);
    ushort* xnb   = (ushort*)(ws + 32 * MB);
    ushort* Ga    = (ushort*)(ws + 64 * MB);
    ushort* Gb    = (ushort*)(ws + 96 * MB);
    ushort* Gog   = (ushort*)(ws + 128 * MB);
    ushort* hff   = (ushort*)(ws + 64 * MB);   // [M,4096] bf16, reuses gate region
    float*  P     = (float*)(ws + 192 * MB);
    float*  Hend  = (float*)(ws + 193 * MB);
    float*  Carry = (float*)(ws + 194 * MB);

    // 0) weights -> bf16 [N,K]
    transpose_cast_gates<<<dim3(32, 32, 4), 256, 0, stream>>>(
        w_input, w_forget, w_igate, w_ogate, wtG1, wtG2);
    transpose_cast_kernel<<<dim3(DFF/32, Dd/32), 256, 0, stream>>>(w_fc,     wtFC,  Dd, DFF);
    transpose_cast_kernel<<<dim3(DFF/32, Dd/32), 256, 0, stream>>>(w_fc_act, wtFCA, Dd, DFF);
    transpose_cast_kernel<<<dim3(Dd/32, DFF/32), 256, 0, stream>>>(w_out,    wtOUT, DFF, Dd);

    // 1) xn = rmsnorm(x) -> bf16  (wave-per-row, 4 rows/block)
    rmsnorm_bf16_kernel<<<Mm / 4, 256, 0, stream>>>(x, norm1_w, xnb);

    // 2) all four gates in one dual-GEMM (N = 2048), 256x128 tiles, 2-phase
    mfma_gemm_gates<<<(2048/128) * (Mm/256), 512, 0, stream>>>(
        xnb, wtG1, wtG2, b_input, b_forget, b_igate, b_ogate, Ga, Gb, Gog);

    // 3) chunked scan + fused ogate/residual + fused rmsnorm2
    dim3 sg(CH, Bb);
    scan_pass1<<<sg, 256, 0, stream>>>(Ga, Gb, P, Hend);
    scan_pass2<<<(Bb * Dd) / 64, 64, 0, stream>>>(P, Hend, h0, Carry);
    scan_pass3_norm<<<dim3(CH / 2, Bb), 512, 0, stream>>>(
        Ga, Gb, Gog, Carry, x, norm2_w, out, xnb);

    // 4) hff = (xn2@w_fc + b) * silu(xn2@w_fc_act + b)  -> bf16 [M,4096]
    mfma_gemm_swiglu<<<(DFF/128) * (Mm/256), 512, 0, stream>>>(
        xnb, wtFC, b_fc, wtFCA, b_fc_act, hff);

    // 5) out = hff @ w_out + b_out + x1   (in-place on d_out)
    mfma_gemm_residual<<<(Dd/256) * (Mm/256), 512, 0, stream>>>(
        hff, wtOUT, b_out, out);
}

// Round 8
// 886.354 us; speedup vs baseline: 1.0005x; 1.0005x over previous
//
#include <hip/hip_runtime.h>
#include <math.h>
#include <stdint.h>

// Problem dims (fixed by reference)
static constexpr int Bb  = 4;
static constexpr int Ll  = 4096;
static constexpr int Dd  = 1024;
static constexpr int DFF = 4096;
static constexpr int Mm  = Bb * Ll;     // 16384 rows
static constexpr int CH  = 64;          // scan chunks
static constexpr int CS  = Ll / CH;     // 64 steps per chunk
static constexpr float EPS = 1e-6f;

typedef __attribute__((ext_vector_type(8)))  short short8;      // 8 bf16 (4 VGPRs)
typedef __attribute__((ext_vector_type(16))) float floatx16;    // 32x32 MFMA C/D
typedef __attribute__((ext_vector_type(4)))  unsigned short us4;

__device__ __forceinline__ float sigmoidf_(float v) { return 1.0f / (1.0f + __expf(-v)); }
// safe at +-inf: 2*sigmoid(2x)-1
__device__ __forceinline__ float fast_tanh(float x) {
    return 2.0f / (1.0f + __expf(-2.0f * x)) - 1.0f;
}
__device__ __forceinline__ ushort f2bf(float f) {
    union { float f; uint32_t u; } v; v.f = f;
    return (ushort)((v.u + 0x7FFFu + ((v.u >> 16) & 1u)) >> 16);   // RNE
}
__device__ __forceinline__ float bf2f(ushort h) {
    union { uint32_t u; float f; } v; v.u = (uint32_t)h << 16; return v.f;
}

// async global->LDS, 16 bytes per lane (wave-uniform base + lane*16 layout)
__device__ __forceinline__ void gload16(const ushort* g, ushort* l) {
    __builtin_amdgcn_global_load_lds(
        (const __attribute__((address_space(1))) uint32_t*)g,
        (__attribute__((address_space(3))) uint32_t*)l, 16, 0, 0);
}

// ===========================================================================
// 2-phase pipelined dual-GEMM core, 512 thr / 8 waves, BK=64 — 32x32x16 MFMA.
//   R7 post-mortem: READ_HEAD split regressed (revert to grouped reads);
//   5 schedule variants all 39-42% MfmaUtil; per-K-tile ledger per CU =
//   MFMA 2483 + DS 2816 ~= measured 5600 (strict sum).  This round reduces
//   the MFMA term itself: mfma_f32_32x32x16_bf16 (8.07 cyc / 32768 FLOP,
//   vs 4.85 / 16384) -> MFMA term 2066 cyc at IDENTICAL DS traffic
//   (12 ds_read_b128 + 16 MFMA per kk-half per wave; wave tile 128x32-dual).
//   Layouts (guide-verified): C/D col=lane&31, row=(reg&3)+8*(reg>>2)
//   +4*(lane>>5) [m74/m101]; A/B input row=lane&31, k=8*(lane>>5)+j.
//   LDS tile [row][32k] with 16B-chunk XOR swizzle: global k-chunk g of
//   row m stored at slot g^((m>>1)&3); read slot sl[ks] = (ks*2+h)^rsw,
//   rsw = ((lane&31)>>1)&3 (wr*128, mi*32, wc*32 are 8-row aligned -> drop
//   out of (row>>1)&3).  Bank check: rows 0-7 x swizzled slots cover all
//   32 banks exactly once -> equal 8-words/bank distribution = 0 conflicts.
//   Schedule unchanged from R6: {12 ds_read; stage 8; MFMA cluster} per
//   kk-half, 2 barriers/K-tile, counted vmcnt (8 then 4, never 0 mid-loop),
//   last K-tile peeled.  Race/deadlock audit as R6.
// ===========================================================================
static constexpr int HT_US  = 256 * 32;       // ushorts per half-tile (16 KB)
static constexpr int BUF_US = 4 * HT_US;      // per buffer (64 KB)

__device__ __forceinline__ void gemm_core_2ph(
    const ushort* __restrict__ A, const ushort* __restrict__ B1,
    const ushort* __restrict__ B2, int m0, int n0b1, int n0b2, int K,
    ushort* lds, floatx16 (&acc1)[4], floatx16 (&acc2)[4])
{
    const int tid = threadIdx.x;
    const int mm = tid >> 2, ss = tid & 3;
    const int kb = ss ^ ((mm >> 1) & 3);          // swizzled k-slot (staging)
    const ushort* pA0 = A  + (size_t)(m0 + mm) * K + kb * 8;
    const ushort* pA1 = pA0 + (size_t)128 * K;
    const ushort* pB0 = B1 + (size_t)(n0b1 + mm) * K + kb * 8;
    const ushort* pB1 = B2 + (size_t)(n0b2 + mm) * K + kb * 8;

    const int wave = tid >> 6, lane = tid & 63;
    const int wr = wave >> 2, wc = wave & 3;      // 2M x 4N wave grid
    const int l31 = lane & 31, hh = lane >> 5;
    const int rsw = (l31 >> 1) & 3;               // row-driven slot swizzle
    int sl[2];                                    // slot byte-offsets (ushorts)
    sl[0] = ((0 * 2 + hh) ^ rsw) << 3;
    sl[1] = ((1 * 2 + hh) ^ rsw) << 3;
    int aofs[4];
    #pragma unroll
    for (int mi = 0; mi < 4; ++mi)
        aofs[mi] = (wr * 128 + mi * 32 + l31) * 32;
    const int bofs = 2 * HT_US + (wc * 32 + l31) * 32;

    const int NT = K >> 6;

    // Issue order: {A0,B0} (4 loads) then {A1,B1} (4) -> vmcnt groups of 4.
#define STG_TILE(bsel, tt) do { \
        ushort* dA0 = lds + (bsel) * BUF_US; \
        ushort* dA1 = dA0 + HT_US; \
        ushort* dB0 = dA0 + 2 * HT_US; \
        ushort* dB1 = dA0 + 3 * HT_US; \
        int o0 = (tt) * 64, o1 = o0 + 32; \
        gload16(pA0 + o0, dA0 + tid * 8); gload16(pA1 + o0, dA0 + (tid + 512) * 8); \
        gload16(pB0 + o0, dB0 + tid * 8); gload16(pB1 + o0, dB0 + (tid + 512) * 8); \
        gload16(pA0 + o1, dA1 + tid * 8); gload16(pA1 + o1, dA1 + (tid + 512) * 8); \
        gload16(pB0 + o1, dB1 + tid * 8); gload16(pB1 + o1, dB1 + (tid + 512) * 8); } while (0)

#define READ_FRAGS(base) do { \
        _Pragma("unroll") \
        for (int mi_ = 0; mi_ < 4; ++mi_) { \
            a[mi_][0] = *(const short8*)&(base)[aofs[mi_] + sl[0]]; \
            a[mi_][1] = *(const short8*)&(base)[aofs[mi_] + sl[1]]; \
        } \
        _Pragma("unroll") \
        for (int ks_ = 0; ks_ < 2; ++ks_) { \
            b[ks_]  = *(const short8*)&(base)[bofs + sl[ks_]]; \
            cc[ks_] = *(const short8*)&(base)[bofs + 4096 + sl[ks_]]; \
        } } while (0)

#define MFMA_FULL() do { \
        __builtin_amdgcn_s_setprio(1); \
        _Pragma("unroll") \
        for (int ks_ = 0; ks_ < 2; ++ks_) \
            _Pragma("unroll") \
            for (int mi_ = 0; mi_ < 4; ++mi_) { \
                acc1[mi_] = __builtin_amdgcn_mfma_f32_32x32x16_bf16(a[mi_][ks_], b[ks_],  acc1[mi_], 0, 0, 0); \
                acc2[mi_] = __builtin_amdgcn_mfma_f32_32x32x16_bf16(a[mi_][ks_], cc[ks_], acc2[mi_], 0, 0, 0); \
            } \
        __builtin_amdgcn_s_setprio(0); } while (0)

    // ---- prologue: stage K-tile 0; keep its kk1 halves in flight ----
    STG_TILE(0, 0);
    asm volatile("s_waitcnt vmcnt(4)" ::: "memory");
    __builtin_amdgcn_s_barrier();

    int t = 0;
    for (; t < NT - 1; ++t) {
        const int buf = t & 1, nbuf = buf ^ 1;
        const ushort* Ab = lds + buf * BUF_US;
        short8 a[4][2], b[2], cc[2];

        // ---------- phase 0: kk0 (12 ds_read + stage tile t+1 + 16 MFMA) ----
        READ_FRAGS(Ab);
        STG_TILE(nbuf, t + 1);
        MFMA_FULL();
        asm volatile("s_waitcnt vmcnt(8)" ::: "memory");
        __builtin_amdgcn_s_barrier();

        // ---------- phase 1: kk1 (12 ds_read + 16 MFMA) ----------
        const ushort* Ab1 = Ab + HT_US;
        READ_FRAGS(Ab1);
        MFMA_FULL();
        asm volatile("s_waitcnt vmcnt(4)" ::: "memory");
        __builtin_amdgcn_s_barrier();
    }
    // ---- epilogue: last K-tile (no prefetch) ----
    {
        const int buf = t & 1;
        const ushort* Ab = lds + buf * BUF_US;
        short8 a[4][2], b[2], cc[2];
        READ_FRAGS(Ab);
        MFMA_FULL();
        asm volatile("s_waitcnt vmcnt(0)" ::: "memory");
        __builtin_amdgcn_s_barrier();
        const ushort* Ab1 = Ab + HT_US;
        READ_FRAGS(Ab1);
        MFMA_FULL();
    }
#undef STG_TILE
#undef READ_FRAGS
#undef MFMA_FULL
}

// C/D mapping helper: reg r, lane -> row offset within the 32-row block
#define CD_ROW(r, hh) (((r) & 3) + 8 * ((r) >> 2) + 4 * (hh))

// ---------------------------------------------------------------------------
// Fused QuasiLSTM gate GEMM (dual, shared A), N = 2048:
//   W1t rows [0,1024) = w_input^T,  [1024,2048) = w_forget^T
//   W2t rows [0,1024) = w_igate^T,  [1024,2048) = w_ogate^T
// col <  1024:  Gb  = tanh(z1) * sigmoid(z2)
// col >= 1024:  Ga  = sigmoid(z1);  Gog = sigmoid(z2)
// ---------------------------------------------------------------------------
__global__ __launch_bounds__(512) void mfma_gemm_gates(
    const ushort* __restrict__ A, const ushort* __restrict__ W1t,
    const ushort* __restrict__ W2t,
    const float* __restrict__ b_input, const float* __restrict__ b_forget,
    const float* __restrict__ b_igate, const float* __restrict__ b_ogate,
    ushort* __restrict__ Ga, ushort* __restrict__ Gb, ushort* __restrict__ Gog)
{
    __shared__ __align__(16) ushort lds[2 * BUF_US];
    // XCD-slice swizzle: each XCD owns 2 bx columns (B-slice 1MB, L2-resident)
    int xcd = blockIdx.x & 7, i = blockIdx.x >> 3;   // i in [0,128)
    int bx = xcd * 2 + (i & 1), by = i >> 1;
    int m0 = by * 256, n0 = bx * 128;

    floatx16 acc1[4] = {};
    floatx16 acc2[4] = {};
    gemm_core_2ph(A, W1t, W2t, m0, n0, n0, Dd, lds, acc1, acc2);

    int tid = threadIdx.x, wave = tid >> 6, lane = tid & 63;
    int wr = wave >> 2, wc = wave & 3, l31 = lane & 31, hh = lane >> 5;
    int col = n0 + wc * 32 + l31;                 // [0,2048)
    if (col < 1024) {
        float b1v = b_input[col], b2v = b_igate[col];
        #pragma unroll
        for (int mi = 0; mi < 4; ++mi)
            #pragma unroll
            for (int r = 0; r < 16; ++r) {
                int row = m0 + wr * 128 + mi * 32 + CD_ROW(r, hh);
                float z1 = acc1[mi][r] + b1v;
                float z2 = acc2[mi][r] + b2v;
                Gb[(size_t)row * Dd + col] = f2bf(fast_tanh(z1) * sigmoidf_(z2));
            }
    } else {
        int c2 = col - 1024;
        float b1v = b_forget[c2], b2v = b_ogate[c2];
        #pragma unroll
        for (int mi = 0; mi < 4; ++mi)
            #pragma unroll
            for (int r = 0; r < 16; ++r) {
                int row = m0 + wr * 128 + mi * 32 + CD_ROW(r, hh);
                float z1 = acc1[mi][r] + b1v;
                float z2 = acc2[mi][r] + b2v;
                Ga[(size_t)row * Dd + c2]  = f2bf(sigmoidf_(z1));
                Gog[(size_t)row * Dd + c2] = f2bf(sigmoidf_(z2));
            }
    }
}

// ---------------------------------------------------------------------------
// MFMA dual GEMM for SwiGLU: C = (A@W1+b1) * silu(A@W2+b2), bf16 out
// ---------------------------------------------------------------------------
__global__ __launch_bounds__(512) void mfma_gemm_swiglu(
    const ushort* __restrict__ A, const ushort* __restrict__ W1t,
    const float* __restrict__ b1, const ushort* __restrict__ W2t,
    const float* __restrict__ b2, ushort* __restrict__ C)
{
    __shared__ __align__(16) ushort lds[2 * BUF_US];
    // XCD-slice swizzle: each XCD owns 4 bx columns (B-slice 2MB, L2-resident)
    int xcd = blockIdx.x & 7, i = blockIdx.x >> 3;   // i in [0,256)
    int bx = xcd * 4 + (i & 3), by = i >> 2;
    int m0 = by * 256, n0 = bx * 128;

    floatx16 acc1[4] = {};
    floatx16 acc2[4] = {};
    gemm_core_2ph(A, W1t, W2t, m0, n0, n0, Dd, lds, acc1, acc2);

    int tid = threadIdx.x, wave = tid >> 6, lane = tid & 63;
    int wr = wave >> 2, wc = wave & 3, l31 = lane & 31, hh = lane >> 5;
    int col = n0 + wc * 32 + l31;
    float b1v = b1[col], b2v = b2[col];
    #pragma unroll
    for (int mi = 0; mi < 4; ++mi)
        #pragma unroll
        for (int r = 0; r < 16; ++r) {
            int row = m0 + wr * 128 + mi * 32 + CD_ROW(r, hh);
            float z1 = acc1[mi][r] + b1v;
            float z2 = acc2[mi][r] + b2v;
            C[(size_t)row * DFF + col] = f2bf(z1 * z2 * sigmoidf_(z2));
        }
}

// ---------------------------------------------------------------------------
// MFMA residual GEMM: out_f32 = A_bf16[M,K] @ Wt[N,K]^T + bias + R (R == out)
// Single-B: the 256-wide N tile is two 128 halves (acc1/acc2).
// ---------------------------------------------------------------------------
__global__ __launch_bounds__(512) void mfma_gemm_residual(
    const ushort* __restrict__ A, const ushort* __restrict__ Wt,
    const float* __restrict__ bias, float* __restrict__ C)
{
    __shared__ __align__(16) ushort lds[2 * BUF_US];
    int xcd = blockIdx.x & 7, i = blockIdx.x >> 3;   // i in [0,32)
    int s = xcd * 32 + i;
    int bx = s & 3, by = s >> 2;                     // bx fast: A-panel reuse
    int m0 = by * 256, n0 = bx * 256;

    floatx16 acc1[4] = {};
    floatx16 acc2[4] = {};
    gemm_core_2ph(A, Wt, Wt, m0, n0, n0 + 128, DFF, lds, acc1, acc2);

    int tid = threadIdx.x, wave = tid >> 6, lane = tid & 63;
    int wr = wave >> 2, wc = wave & 3, l31 = lane & 31, hh = lane >> 5;
    int col1 = n0 + wc * 32 + l31;
    int col2 = col1 + 128;
    float bs1 = bias[col1], bs2 = bias[col2];
    #pragma unroll
    for (int mi = 0; mi < 4; ++mi)
        #pragma unroll
        for (int r = 0; r < 16; ++r) {
            int row = m0 + wr * 128 + mi * 32 + CD_ROW(r, hh);
            size_t i1 = (size_t)row * Dd + col1;
            size_t i2 = (size_t)row * Dd + col2;
            C[i1] = acc1[mi][r] + bs1 + C[i1];  // same-thread RMW
            C[i2] = acc2[mi][r] + bs2 + C[i2];
        }
}

// ---------------------------------------------------------------------------
// Weight cast+transpose: W fp32 [K,N] -> Wt bf16 [N,K]
// ---------------------------------------------------------------------------
__global__ __launch_bounds__(256) void transpose_cast_kernel(
    const float* __restrict__ W, ushort* __restrict__ Wt, int K, int N)
{
    __shared__ float t[32][33];
    int lx = threadIdx.x & 31, ly = threadIdx.x >> 5;   // 32 x 8
    int n = blockIdx.x * 32 + lx;
    #pragma unroll
    for (int i = 0; i < 4; ++i) {
        int k = blockIdx.y * 32 + ly + i * 8;
        t[ly + i * 8][lx] = W[(size_t)k * N + n];
    }
    __syncthreads();
    int k2 = blockIdx.y * 32 + lx;
    #pragma unroll
    for (int i = 0; i < 4; ++i) {
        int n2 = blockIdx.x * 32 + ly + i * 8;
        Wt[(size_t)n2 * K + k2] = f2bf(t[lx][ly + i * 8]);
    }
}

// Batched version for the four 1024x1024 gate weights (grid.z picks source).
__global__ __launch_bounds__(256) void transpose_cast_gates(
    const float* __restrict__ w_i, const float* __restrict__ w_f,
    const float* __restrict__ w_g, const float* __restrict__ w_o,
    ushort* __restrict__ W1t, ushort* __restrict__ W2t)
{
    int z = blockIdx.z;
    const float* W = (z == 0) ? w_i : (z == 1) ? w_f : (z == 2) ? w_g : w_o;
    ushort* Wt = (z == 0) ? W1t : (z == 1) ? W1t + (size_t)1024 * Dd
               : (z == 2) ? W2t : W2t + (size_t)1024 * Dd;
    __shared__ float t[32][33];
    int lx = threadIdx.x & 31, ly = threadIdx.x >> 5;
    int n = blockIdx.x * 32 + lx;
    #pragma unroll
    for (int i = 0; i < 4; ++i) {
        int k = blockIdx.y * 32 + ly + i * 8;
        t[ly + i * 8][lx] = W[(size_t)k * Dd + n];
    }
    __syncthreads();
    int k2 = blockIdx.y * 32 + lx;
    #pragma unroll
    for (int i = 0; i < 4; ++i) {
        int n2 = blockIdx.x * 32 + ly + i * 8;
        Wt[(size_t)n2 * Dd + k2] = f2bf(t[lx][ly + i * 8]);
    }
}

// ---------------------------------------------------------------------------
// RMSNorm fp32 in -> bf16 out.  One WAVE per row (4 rows/block):
// pure shfl_xor reduce — no LDS, no __syncthreads.
// ---------------------------------------------------------------------------
__global__ __launch_bounds__(256) void rmsnorm_bf16_kernel(
    const float* __restrict__ x, const float* __restrict__ w,
    ushort* __restrict__ o)
{
    int wave = threadIdx.x >> 6, lane = threadIdx.x & 63;
    int row = blockIdx.x * 4 + wave;
    const float4* xr = (const float4*)(x + (size_t)row * Dd);
    float4 v[4];
    float ss = 0.f;
    #pragma unroll
    for (int j = 0; j < 4; ++j) {
        v[j] = xr[lane + j * 64];
        ss += v[j].x * v[j].x + v[j].y * v[j].y + v[j].z * v[j].z + v[j].w * v[j].w;
    }
    #pragma unroll
    for (int off = 1; off < 64; off <<= 1) ss += __shfl_xor(ss, off, 64);
    float scale = rsqrtf(ss * (1.0f / Dd) + EPS);
    #pragma unroll
    for (int j = 0; j < 4; ++j) {
        float4 wv = ((const float4*)w)[lane + j * 64];
        us4 ov;
        ov.x = f2bf(v[j].x * scale * wv.x);
        ov.y = f2bf(v[j].y * scale * wv.y);
        ov.z = f2bf(v[j].z * scale * wv.z);
        ov.w = f2bf(v[j].w * scale * wv.w);
        *(us4*)&o[(size_t)row * Dd + (lane + j * 64) * 4] = ov;
    }
}

// ---------------------------------------------------------------------------
// Chunked linear recurrence, 4 channels/thread (ushort4 loads)
// ---------------------------------------------------------------------------
__global__ __launch_bounds__(256) void scan_pass1(
    const ushort* __restrict__ Ga, const ushort* __restrict__ Gb,
    float* __restrict__ P, float* __restrict__ Hend)
{
    int tid = threadIdx.x;
    int c = blockIdx.x, b = blockIdx.y;
    size_t base = ((size_t)b * Ll + (size_t)c * CS) * Dd + tid * 4;
    float p[4] = {1.f, 1.f, 1.f, 1.f};
    float h[4] = {};
    #pragma unroll 4
    for (int t = 0; t < CS; ++t) {
        us4 av = *(const us4*)&Ga[base + (size_t)t * Dd];
        us4 bv = *(const us4*)&Gb[base + (size_t)t * Dd];
        #pragma unroll
        for (int j = 0; j < 4; ++j) {
            float aa = bf2f(av[j]);
            float bb = bf2f(bv[j]);
            p[j] *= aa;
            h[j] = aa * h[j] + bb;
        }
    }
    size_t o = ((size_t)b * CH + c) * Dd + tid * 4;
    *(float4*)&P[o]    = make_float4(p[0], p[1], p[2], p[3]);
    *(float4*)&Hend[o] = make_float4(h[0], h[1], h[2], h[3]);
}

// 64-thread blocks: spread the 4096 serial carry chains over 64 CUs.
__global__ __launch_bounds__(64) void scan_pass2(
    const float* __restrict__ P, const float* __restrict__ Hend,
    const float* __restrict__ h0, float* __restrict__ Carry)
{
    int idx = blockIdx.x * 64 + threadIdx.x;  // B*D = 4096
    int b = idx / Dd, d = idx % Dd;
    float carry = h0[d];
    for (int c = 0; c < CH; ++c) {
        size_t o = ((size_t)b * CH + c) * Dd + d;
        Carry[o] = carry;
        carry = P[o] * carry + Hend[o];
    }
}

// Replay with carry + fused ogate/residual + fused RMSNorm2.
// 512 threads / 2 chunks per block; software-pipelined reduction:
// ONE __syncthreads per step (read red[t&1], pre-write red[(t+1)&1]).
__global__ __launch_bounds__(512) void scan_pass3_norm(
    const ushort* __restrict__ Ga, const ushort* __restrict__ Gb,
    const ushort* __restrict__ Gog, const float* __restrict__ Carry,
    const float* __restrict__ x, const float* __restrict__ norm2w,
    float* __restrict__ x1, ushort* __restrict__ xnb)
{
    int tid = threadIdx.x;
    int half = tid >> 8, ltid = tid & 255;
    int c = blockIdx.x * 2 + half, b = blockIdx.y;
    size_t base = ((size_t)b * Ll + (size_t)c * CS) * Dd + ltid * 4;
    float4 h4 = *(const float4*)&Carry[((size_t)b * CH + c) * Dd + ltid * 4];
    float h[4] = {h4.x, h4.y, h4.z, h4.w};
    float4 w4 = ((const float4*)norm2w)[ltid];
    float wv[4] = {w4.x, w4.y, w4.z, w4.w};
    __shared__ float red[2][2][4];    // [parity][half][wave-of-half]

    float v[4];
    // ---- prologue: step 0 ----
    {
        us4 av = *(const us4*)&Ga[base];
        us4 bv = *(const us4*)&Gb[base];
        us4 gv = *(const us4*)&Gog[base];
        float4 xv = *(const float4*)&x[base];
        float xs[4] = {xv.x, xv.y, xv.z, xv.w};
        #pragma unroll
        for (int j = 0; j < 4; ++j) {
            float aa = bf2f(av[j]);
            float bb = bf2f(bv[j]);
            h[j] = aa * h[j] + bb;
            v[j] = fast_tanh(h[j]) * bf2f(gv[j]) + xs[j];
        }
        *(float4*)&x1[base] = make_float4(v[0], v[1], v[2], v[3]);
        float ss = v[0]*v[0] + v[1]*v[1] + v[2]*v[2] + v[3]*v[3];
        #pragma unroll
        for (int off = 32; off > 0; off >>= 1) ss += __shfl_down(ss, off, 64);
        if ((ltid & 63) == 0) red[0][half][ltid >> 6] = ss;
    }
    __syncthreads();

    for (int t = 0; t < CS; ++t) {
        int p = t & 1;
        float scale = rsqrtf((red[p][half][0] + red[p][half][1] +
                              red[p][half][2] + red[p][half][3]) * (1.0f / Dd) + EPS);
        us4 ov;
        #pragma unroll
        for (int j = 0; j < 4; ++j) ov[j] = f2bf(v[j] * scale * wv[j]);
        *(us4*)&xnb[base + (size_t)t * Dd] = ov;

        if (t + 1 < CS) {
            size_t i = base + (size_t)(t + 1) * Dd;
            us4 av = *(const us4*)&Ga[i];
            us4 bv = *(const us4*)&Gb[i];
            us4 gv = *(const us4*)&Gog[i];
            float4 xv = *(const float4*)&x[i];
            float xs[4] = {xv.x, xv.y, xv.z, xv.w};
            #pragma unroll
            for (int j = 0; j < 4; ++j) {
                float aa = bf2f(av[j]);
                float bb = bf2f(bv[j]);
                h[j] = aa * h[j] + bb;
                v[j] = fast_tanh(h[j]) * bf2f(gv[j]) + xs[j];
            }
            *(float4*)&x1[i] = make_float4(v[0], v[1], v[2], v[3]);
            float ss = v[0]*v[0] + v[1]*v[1] + v[2]*v[2] + v[3]*v[3];
            #pragma unroll
            for (int off = 32; off > 0; off >>= 1) ss += __shfl_down(ss, off, 64);
            if ((ltid & 63) == 0) red[(t + 1) & 1][half][ltid >> 6] = ss;
        }
        __syncthreads();
    }
}

// ---------------------------------------------------------------------------
// Launch. Workspace (195 MB):
//   [0,4)   MB: W1t gates bf16 [2048,1024]   (input | forget)
//   [4,8)   MB: W2t gates bf16 [2048,1024]   (igate | ogate)
//   [8,16)  MB: wtFC   [16,24) MB: wtFCA   [24,32) MB: wtOUT
//   [32,64) MB: xnb bf16 [M,1024]
//   [64,192)MB: Ga/Gb/Gog bf16 (32MB each) -> later hff bf16 [M,4096]
//   [192,195)MB: P, Hend, Carry fp32
// d_out doubles as x1 then final out.
// ---------------------------------------------------------------------------
extern "C" void kernel_launch(void* const* d_in, const int* in_sizes, int n_in,
                              void* d_out, int out_size, void* d_ws, size_t ws_size,
                              hipStream_t stream)
{
    const float* x        = (const float*)d_in[0];
    const float* w_forget = (const float*)d_in[1];
    const float* b_forget = (const float*)d_in[2];
    const float* w_input  = (const float*)d_in[3];
    const float* b_input  = (const float*)d_in[4];
    const float* w_igate  = (const float*)d_in[5];
    const float* b_igate  = (const float*)d_in[6];
    const float* w_ogate  = (const float*)d_in[7];
    const float* b_ogate  = (const float*)d_in[8];
    const float* h0       = (const float*)d_in[9];
    const float* norm1_w  = (const float*)d_in[10];
    const float* norm2_w  = (const float*)d_in[11];
    const float* w_fc     = (const float*)d_in[12];
    const float* b_fc     = (const float*)d_in[13];
    const float* w_fc_act = (const float*)d_in[14];
    const float* b_fc_act = (const float*)d_in[15];
    const float* w_out    = (const float*)d_in[16];
    const float* b_out    = (const float*)d_in[17];
    float* out = (float*)d_out;   // x1, then final out

    char* ws = (char*)d_ws;
    const size_t MB = 1ull << 20;
    ushort* wtG1  = (ushort*)(ws + 0 * MB);
    ushort* wtG2  = (ushort*)(ws + 4 * MB);
    ushort* wtFC  = (ushort*)(ws + 8 * MB);
    ushort* wtFCA = (ushort*)(ws + 16 * MB);
    ushort* wtOUT = (ushort*)(ws + 24 * MB);
    ushort* xnb   = (ushort*)(ws + 32 * MB);
    ushort* Ga    = (ushort*)(ws + 64 * MB);
    ushort* Gb    = (ushort*)(ws + 96 * MB);
    ushort* Gog   = (ushort*)(ws + 128 * MB);
    ushort* hff   = (ushort*)(ws + 64 * MB);   // [M,4096] bf16, reuses gate region
    float*  P     = (float*)(ws + 192 * MB);
    float*  Hend  = (float*)(ws + 193 * MB);
    float*  Carry = (float*)(ws + 194 * MB);

    // 0) weights -> bf16 [N,K]
    transpose_cast_gates<<<dim3(32, 32, 4), 256, 0, stream>>>(
        w_input, w_forget, w_igate, w_ogate, wtG1, wtG2);
    transpose_cast_kernel<<<dim3(DFF/32, Dd/32), 256, 0, stream>>>(w_fc,     wtFC,  Dd, DFF);
    transpose_cast_kernel<<<dim3(DFF/32, Dd/32), 256, 0, stream>>>(w_fc_act, wtFCA, Dd, DFF);
    transpose_cast_kernel<<<dim3(Dd/32, DFF/32), 256, 0, stream>>>(w_out,    wtOUT, DFF, Dd);

    // 1) xn = rmsnorm(x) -> bf16  (wave-per-row, 4 rows/block)
    rmsnorm_bf16_kernel<<<Mm / 4, 256, 0, stream>>>(x, norm1_w, xnb);

    // 2) all four gates in one dual-GEMM (N = 2048), 256x128 tiles, 2-phase
    mfma_gemm_gates<<<(2048/128) * (Mm/256), 512, 0, stream>>>(
        xnb, wtG1, wtG2, b_input, b_forget, b_igate, b_ogate, Ga, Gb, Gog);

    // 3) chunked scan + fused ogate/residual + fused rmsnorm2
    dim3 sg(CH, Bb);
    scan_pass1<<<sg, 256, 0, stream>>>(Ga, Gb, P, Hend);
    scan_pass2<<<(Bb * Dd) / 64, 64, 0, stream>>>(P, Hend, h0, Carry);
    scan_pass3_norm<<<dim3(CH / 2, Bb), 512, 0, stream>>>(
        Ga, Gb, Gog, Carry, x, norm2_w, out, xnb);

    // 4) hff = (xn2@w_fc + b) * silu(xn2@w_fc_act + b)  -> bf16 [M,4096]
    mfma_gemm_swiglu<<<(DFF/128) * (Mm/256), 512, 0, stream>>>(
        xnb, wtFC, b_fc, wtFCA, b_fc_act, hff);

    // 5) out = hff @ w_out + b_out + x1   (in-place on d_out)
    mfma_gemm_residual<<<(Dd/256) * (Mm/256), 512, 0, stream>>>(
        hff, wtOUT, b_out, out);
}

// Round 9
// 865.738 us; speedup vs baseline: 1.0243x; 1.0238x over previous
//
#include <hip/hip_runtime.h>
#include <math.h>
#include <stdint.h>

// Problem dims (fixed by reference)
static constexpr int Bb  = 4;
static constexpr int Ll  = 4096;
static constexpr int Dd  = 1024;
static constexpr int DFF = 4096;
static constexpr int Mm  = Bb * Ll;     // 16384 rows
static constexpr int CH  = 64;          // scan chunks
static constexpr int CS  = Ll / CH;     // 64 steps per chunk
static constexpr float EPS = 1e-6f;

typedef __attribute__((ext_vector_type(8))) short short8;     // 8 bf16 (4 VGPRs)
typedef __attribute__((ext_vector_type(4))) float floatx4;    // MFMA C/D
typedef __attribute__((ext_vector_type(4))) unsigned short us4;

__device__ __forceinline__ float sigmoidf_(float v) { return 1.0f / (1.0f + __expf(-v)); }
// safe at +-inf: 2*sigmoid(2x)-1
__device__ __forceinline__ float fast_tanh(float x) {
    return 2.0f / (1.0f + __expf(-2.0f * x)) - 1.0f;
}
__device__ __forceinline__ ushort f2bf(float f) {
    union { float f; uint32_t u; } v; v.f = f;
    return (ushort)((v.u + 0x7FFFu + ((v.u >> 16) & 1u)) >> 16);   // RNE
}
__device__ __forceinline__ float bf2f(ushort h) {
    union { uint32_t u; float f; } v; v.u = (uint32_t)h << 16; return v.f;
}

// async global->LDS, 16 bytes per lane (wave-uniform base + lane*16 layout)
__device__ __forceinline__ void gload16(const ushort* g, ushort* l) {
    __builtin_amdgcn_global_load_lds(
        (const __attribute__((address_space(1))) uint32_t*)g,
        (__attribute__((address_space(3))) uint32_t*)l, 16, 0, 0);
}

// ===========================================================================
// 2-phase pipelined dual-GEMM core, 512 thr / 8 waves, BK=64 — 16x16x32 MFMA.
//   R9 = consolidation: this is the R6-measured core (swiglu 301 us, 0 bank
//   conflicts, MfmaUtil 42%).  R8's 32x32 port produced 2.5e7 conflicts/
//   dispatch: a wave's b128 read there covered 32 rows x 2 of 4 k-slots
//   (rows r,r+8,r+16,r+24 same bank-start, 4 distinct addrs -> 4-way),
//   whereas THIS pattern's single read covers fr(16 rows) x q(4 slots) = a
//   contiguous 16-row x 64B tile, every chunk once -> minimum free 2-alias.
//   No LDS re-layout fixes 32x32 under global_load_lds's lane-contiguous
//   dest constraint without 4x global sector waste -> 16x16 it is.
//   Schedule: {12 ds_read; stage 8; 32 MFMA} per kk-half, 2 barriers/K-tile,
//   counted vmcnt (8 then 4, never 0 mid-loop), last K-tile peeled.
//   Ledger: prologue stages tile0 (8), vmcnt(4) -> kk0 landed.  Loop ph0:
//   +8 (tile t+1), vmcnt(8) retires {A1,B1(t)}.  ph1: vmcnt(4) retires
//   {A0,B0(t+1)}.  Epilogue drains vmcnt(0).
//   Race-safety: each wave's ds_reads complete before its own MFMAs
//   (compiler lgkm waits) hence before its barrier arrival; writes into a
//   buffer issue only after the barrier all readers passed.
//   Swizzle (0-conflict proven): chunk (m,s) holds k-block s ^ ((m>>1)&3);
//   read slot = q ^ ((fr>>1)&3).
// ===========================================================================
static constexpr int HT_US  = 256 * 32;       // ushorts per half-tile (16 KB)
static constexpr int BUF_US = 4 * HT_US;      // per buffer (64 KB)

__device__ __forceinline__ void gemm_core_2ph(
    const ushort* __restrict__ A, const ushort* __restrict__ B1,
    const ushort* __restrict__ B2, int m0, int n0b1, int n0b2, int K,
    ushort* lds, floatx4 (&acc1)[8][2], floatx4 (&acc2)[8][2])
{
    const int tid = threadIdx.x;
    const int mm = tid >> 2, ss = tid & 3;
    const int kb = ss ^ ((mm >> 1) & 3);          // swizzled k-slot (staging)
    const ushort* pA0 = A  + (size_t)(m0 + mm) * K + kb * 8;
    const ushort* pA1 = pA0 + (size_t)128 * K;
    const ushort* pB0 = B1 + (size_t)(n0b1 + mm) * K + kb * 8;
    const ushort* pB1 = B2 + (size_t)(n0b2 + mm) * K + kb * 8;

    const int wave = tid >> 6, lane = tid & 63;
    const int wr = wave >> 2, wc = wave & 3;      // 2M x 4N wave grid
    const int fr = lane & 15, q = lane >> 4;
    const int slot8 = (q ^ ((fr >> 1) & 3)) << 3;
    const int aoff  = (wr * 128 + fr) * 32 + slot8;             // + mi*512
    const int boff  = 2 * HT_US + (wc * 32 + fr) * 32 + slot8;  // + ni*512 (+4096 side2)

    const int NT = K >> 6;

    // Issue order: {A0,B0} (4 loads) then {A1,B1} (4) -> vmcnt groups of 4.
#define STG_TILE(bsel, tt) do { \
        ushort* dA0 = lds + (bsel) * BUF_US; \
        ushort* dA1 = dA0 + HT_US; \
        ushort* dB0 = dA0 + 2 * HT_US; \
        ushort* dB1 = dA0 + 3 * HT_US; \
        int o0 = (tt) * 64, o1 = o0 + 32; \
        gload16(pA0 + o0, dA0 + tid * 8); gload16(pA1 + o0, dA0 + (tid + 512) * 8); \
        gload16(pB0 + o0, dB0 + tid * 8); gload16(pB1 + o0, dB0 + (tid + 512) * 8); \
        gload16(pA0 + o1, dA1 + tid * 8); gload16(pA1 + o1, dA1 + (tid + 512) * 8); \
        gload16(pB0 + o1, dB1 + tid * 8); gload16(pB1 + o1, dB1 + (tid + 512) * 8); } while (0)

#define READ_FRAGS(base) do { \
        _Pragma("unroll") \
        for (int i_ = 0; i_ < 8; ++i_) a[i_] = *(const short8*)&(base)[aoff + i_ * 512]; \
        _Pragma("unroll") \
        for (int n_ = 0; n_ < 2; ++n_) { \
            b[n_] = *(const short8*)&(base)[boff + n_ * 512]; \
            c[n_] = *(const short8*)&(base)[boff + 4096 + n_ * 512]; \
        } } while (0)

#define MFMA_FULL() do { \
        __builtin_amdgcn_s_setprio(1); \
        _Pragma("unroll") \
        for (int mi_ = 0; mi_ < 8; ++mi_) { \
            acc1[mi_][0] = __builtin_amdgcn_mfma_f32_16x16x32_bf16(a[mi_], b[0], acc1[mi_][0], 0, 0, 0); \
            acc2[mi_][0] = __builtin_amdgcn_mfma_f32_16x16x32_bf16(a[mi_], c[0], acc2[mi_][0], 0, 0, 0); \
            acc1[mi_][1] = __builtin_amdgcn_mfma_f32_16x16x32_bf16(a[mi_], b[1], acc1[mi_][1], 0, 0, 0); \
            acc2[mi_][1] = __builtin_amdgcn_mfma_f32_16x16x32_bf16(a[mi_], c[1], acc2[mi_][1], 0, 0, 0); \
        } \
        __builtin_amdgcn_s_setprio(0); } while (0)

    // ---- prologue: stage K-tile 0; keep its kk1 halves in flight ----
    STG_TILE(0, 0);
    asm volatile("s_waitcnt vmcnt(4)" ::: "memory");
    __builtin_amdgcn_s_barrier();

    int t = 0;
    for (; t < NT - 1; ++t) {
        const int buf = t & 1, nbuf = buf ^ 1;
        const ushort* Ab = lds + buf * BUF_US;
        short8 a[8], b[2], c[2];

        // ---------- phase 0: kk0 (12 ds_read + stage tile t+1 + 32 MFMA) ----
        READ_FRAGS(Ab);
        STG_TILE(nbuf, t + 1);
        MFMA_FULL();
        asm volatile("s_waitcnt vmcnt(8)" ::: "memory");
        __builtin_amdgcn_s_barrier();

        // ---------- phase 1: kk1 (12 ds_read + 32 MFMA) ----------
        const ushort* Ab1 = Ab + HT_US;
        READ_FRAGS(Ab1);
        MFMA_FULL();
        asm volatile("s_waitcnt vmcnt(4)" ::: "memory");
        __builtin_amdgcn_s_barrier();
    }
    // ---- epilogue: last K-tile (no prefetch) ----
    {
        const int buf = t & 1;
        const ushort* Ab = lds + buf * BUF_US;
        short8 a[8], b[2], c[2];
        READ_FRAGS(Ab);
        MFMA_FULL();
        asm volatile("s_waitcnt vmcnt(0)" ::: "memory");
        __builtin_amdgcn_s_barrier();
        const ushort* Ab1 = Ab + HT_US;
        READ_FRAGS(Ab1);
        MFMA_FULL();
    }
#undef STG_TILE
#undef READ_FRAGS
#undef MFMA_FULL
}

// ---------------------------------------------------------------------------
// Fused QuasiLSTM gate GEMM (dual, shared A), N = 2048:
//   W1t rows [0,1024) = w_input^T,  [1024,2048) = w_forget^T
//   W2t rows [0,1024) = w_igate^T,  [1024,2048) = w_ogate^T
// col <  1024:  Gb  = tanh(z1) * sigmoid(z2)
// col >= 1024:  Ga  = sigmoid(z1);  Gog = sigmoid(z2)
// ---------------------------------------------------------------------------
__global__ __launch_bounds__(512) void mfma_gemm_gates(
    const ushort* __restrict__ A, const ushort* __restrict__ W1t,
    const ushort* __restrict__ W2t,
    const float* __restrict__ b_input, const float* __restrict__ b_forget,
    const float* __restrict__ b_igate, const float* __restrict__ b_ogate,
    ushort* __restrict__ Ga, ushort* __restrict__ Gb, ushort* __restrict__ Gog)
{
    __shared__ __align__(16) ushort lds[2 * BUF_US];
    // XCD-slice swizzle: each XCD owns 2 bx columns (B-slice 1MB, L2-resident)
    int xcd = blockIdx.x & 7, i = blockIdx.x >> 3;   // i in [0,128)
    int bx = xcd * 2 + (i & 1), by = i >> 1;
    int m0 = by * 256, n0 = bx * 128;

    floatx4 acc1[8][2] = {};
    floatx4 acc2[8][2] = {};
    gemm_core_2ph(A, W1t, W2t, m0, n0, n0, Dd, lds, acc1, acc2);

    int tid = threadIdx.x, wave = tid >> 6, lane = tid & 63;
    int wr = wave >> 2, wc = wave & 3, fr = lane & 15, q = lane >> 4;
    #pragma unroll
    for (int ni = 0; ni < 2; ++ni) {
        int col = n0 + wc * 32 + ni * 16 + fr;        // [0,2048)
        if (col < 1024) {
            float b1v = b_input[col], b2v = b_igate[col];
            #pragma unroll
            for (int mi = 0; mi < 8; ++mi)
                #pragma unroll
                for (int r = 0; r < 4; ++r) {
                    int row = m0 + wr * 128 + mi * 16 + q * 4 + r;
                    float z1 = acc1[mi][ni][r] + b1v;
                    float z2 = acc2[mi][ni][r] + b2v;
                    Gb[(size_t)row * Dd + col] = f2bf(fast_tanh(z1) * sigmoidf_(z2));
                }
        } else {
            int c2 = col - 1024;
            float b1v = b_forget[c2], b2v = b_ogate[c2];
            #pragma unroll
            for (int mi = 0; mi < 8; ++mi)
                #pragma unroll
                for (int r = 0; r < 4; ++r) {
                    int row = m0 + wr * 128 + mi * 16 + q * 4 + r;
                    float z1 = acc1[mi][ni][r] + b1v;
                    float z2 = acc2[mi][ni][r] + b2v;
                    Ga[(size_t)row * Dd + c2]  = f2bf(sigmoidf_(z1));
                    Gog[(size_t)row * Dd + c2] = f2bf(sigmoidf_(z2));
                }
        }
    }
}

// ---------------------------------------------------------------------------
// MFMA dual GEMM for SwiGLU: C = (A@W1+b1) * silu(A@W2+b2), bf16 out
// ---------------------------------------------------------------------------
__global__ __launch_bounds__(512) void mfma_gemm_swiglu(
    const ushort* __restrict__ A, const ushort* __restrict__ W1t,
    const float* __restrict__ b1, const ushort* __restrict__ W2t,
    const float* __restrict__ b2, ushort* __restrict__ C)
{
    __shared__ __align__(16) ushort lds[2 * BUF_US];
    // XCD-slice swizzle: each XCD owns 4 bx columns (B-slice 2MB, L2-resident)
    int xcd = blockIdx.x & 7, i = blockIdx.x >> 3;   // i in [0,256)
    int bx = xcd * 4 + (i & 3), by = i >> 2;
    int m0 = by * 256, n0 = bx * 128;

    floatx4 acc1[8][2] = {};
    floatx4 acc2[8][2] = {};
    gemm_core_2ph(A, W1t, W2t, m0, n0, n0, Dd, lds, acc1, acc2);

    int tid = threadIdx.x, wave = tid >> 6, lane = tid & 63;
    int wr = wave >> 2, wc = wave & 3, fr = lane & 15, q = lane >> 4;
    #pragma unroll
    for (int ni = 0; ni < 2; ++ni) {
        int col = n0 + wc * 32 + ni * 16 + fr;
        float b1v = b1[col], b2v = b2[col];
        #pragma unroll
        for (int mi = 0; mi < 8; ++mi)
            #pragma unroll
            for (int r = 0; r < 4; ++r) {
                int row = m0 + wr * 128 + mi * 16 + q * 4 + r;
                float z1 = acc1[mi][ni][r] + b1v;
                float z2 = acc2[mi][ni][r] + b2v;
                C[(size_t)row * DFF + col] = f2bf(z1 * z2 * sigmoidf_(z2));
            }
    }
}

// ---------------------------------------------------------------------------
// MFMA residual GEMM: out_f32 = A_bf16[M,K] @ Wt[N,K]^T + bias + R (R == out)
// Single-B: the 256-wide N tile is two 128 halves (acc1/acc2).
// ---------------------------------------------------------------------------
__global__ __launch_bounds__(512) void mfma_gemm_residual(
    const ushort* __restrict__ A, const ushort* __restrict__ Wt,
    const float* __restrict__ bias, float* __restrict__ C)
{
    __shared__ __align__(16) ushort lds[2 * BUF_US];
    int xcd = blockIdx.x & 7, i = blockIdx.x >> 3;   // i in [0,32)
    int s = xcd * 32 + i;
    int bx = s & 3, by = s >> 2;                     // bx fast: A-panel reuse
    int m0 = by * 256, n0 = bx * 256;

    floatx4 acc1[8][2] = {};
    floatx4 acc2[8][2] = {};
    gemm_core_2ph(A, Wt, Wt, m0, n0, n0 + 128, DFF, lds, acc1, acc2);

    int tid = threadIdx.x, wave = tid >> 6, lane = tid & 63;
    int wr = wave >> 2, wc = wave & 3, fr = lane & 15, q = lane >> 4;
    #pragma unroll
    for (int ni = 0; ni < 2; ++ni) {
        int col1 = n0 + wc * 32 + ni * 16 + fr;
        int col2 = col1 + 128;
        float bs1 = bias[col1], bs2 = bias[col2];
        #pragma unroll
        for (int mi = 0; mi < 8; ++mi)
            #pragma unroll
            for (int r = 0; r < 4; ++r) {
                int row = m0 + wr * 128 + mi * 16 + q * 4 + r;
                size_t i1 = (size_t)row * Dd + col1;
                size_t i2 = (size_t)row * Dd + col2;
                C[i1] = acc1[mi][ni][r] + bs1 + C[i1];  // same-thread RMW
                C[i2] = acc2[mi][ni][r] + bs2 + C[i2];
            }
    }
}

// ---------------------------------------------------------------------------
// Weight cast+transpose: W fp32 [K,N] -> Wt bf16 [N,K]
// ---------------------------------------------------------------------------
__global__ __launch_bounds__(256) void transpose_cast_kernel(
    const float* __restrict__ W, ushort* __restrict__ Wt, int K, int N)
{
    __shared__ float t[32][33];
    int lx = threadIdx.x & 31, ly = threadIdx.x >> 5;   // 32 x 8
    int n = blockIdx.x * 32 + lx;
    #pragma unroll
    for (int i = 0; i < 4; ++i) {
        int k = blockIdx.y * 32 + ly + i * 8;
        t[ly + i * 8][lx] = W[(size_t)k * N + n];
    }
    __syncthreads();
    int k2 = blockIdx.y * 32 + lx;
    #pragma unroll
    for (int i = 0; i < 4; ++i) {
        int n2 = blockIdx.x * 32 + ly + i * 8;
        Wt[(size_t)n2 * K + k2] = f2bf(t[lx][ly + i * 8]);
    }
}

// Batched version for the four 1024x1024 gate weights (grid.z picks source).
__global__ __launch_bounds__(256) void transpose_cast_gates(
    const float* __restrict__ w_i, const float* __restrict__ w_f,
    const float* __restrict__ w_g, const float* __restrict__ w_o,
    ushort* __restrict__ W1t, ushort* __restrict__ W2t)
{
    int z = blockIdx.z;
    const float* W = (z == 0) ? w_i : (z == 1) ? w_f : (z == 2) ? w_g : w_o;
    ushort* Wt = (z == 0) ? W1t : (z == 1) ? W1t + (size_t)1024 * Dd
               : (z == 2) ? W2t : W2t + (size_t)1024 * Dd;
    __shared__ float t[32][33];
    int lx = threadIdx.x & 31, ly = threadIdx.x >> 5;
    int n = blockIdx.x * 32 + lx;
    #pragma unroll
    for (int i = 0; i < 4; ++i) {
        int k = blockIdx.y * 32 + ly + i * 8;
        t[ly + i * 8][lx] = W[(size_t)k * Dd + n];
    }
    __syncthreads();
    int k2 = blockIdx.y * 32 + lx;
    #pragma unroll
    for (int i = 0; i < 4; ++i) {
        int n2 = blockIdx.x * 32 + ly + i * 8;
        Wt[(size_t)n2 * Dd + k2] = f2bf(t[lx][ly + i * 8]);
    }
}

// ---------------------------------------------------------------------------
// RMSNorm fp32 in -> bf16 out.  One WAVE per row (4 rows/block):
// pure shfl_xor reduce — no LDS, no __syncthreads.
// ---------------------------------------------------------------------------
__global__ __launch_bounds__(256) void rmsnorm_bf16_kernel(
    const float* __restrict__ x, const float* __restrict__ w,
    ushort* __restrict__ o)
{
    int wave = threadIdx.x >> 6, lane = threadIdx.x & 63;
    int row = blockIdx.x * 4 + wave;
    const float4* xr = (const float4*)(x + (size_t)row * Dd);
    float4 v[4];
    float ss = 0.f;
    #pragma unroll
    for (int j = 0; j < 4; ++j) {
        v[j] = xr[lane + j * 64];
        ss += v[j].x * v[j].x + v[j].y * v[j].y + v[j].z * v[j].z + v[j].w * v[j].w;
    }
    #pragma unroll
    for (int off = 1; off < 64; off <<= 1) ss += __shfl_xor(ss, off, 64);
    float scale = rsqrtf(ss * (1.0f / Dd) + EPS);
    #pragma unroll
    for (int j = 0; j < 4; ++j) {
        float4 wv = ((const float4*)w)[lane + j * 64];
        us4 ov;
        ov.x = f2bf(v[j].x * scale * wv.x);
        ov.y = f2bf(v[j].y * scale * wv.y);
        ov.z = f2bf(v[j].z * scale * wv.z);
        ov.w = f2bf(v[j].w * scale * wv.w);
        *(us4*)&o[(size_t)row * Dd + (lane + j * 64) * 4] = ov;
    }
}

// ---------------------------------------------------------------------------
// Chunked linear recurrence, 4 channels/thread (ushort4 loads)
// ---------------------------------------------------------------------------
__global__ __launch_bounds__(256) void scan_pass1(
    const ushort* __restrict__ Ga, const ushort* __restrict__ Gb,
    float* __restrict__ P, float* __restrict__ Hend)
{
    int tid = threadIdx.x;
    int c = blockIdx.x, b = blockIdx.y;
    size_t base = ((size_t)b * Ll + (size_t)c * CS) * Dd + tid * 4;
    float p[4] = {1.f, 1.f, 1.f, 1.f};
    float h[4] = {};
    #pragma unroll 4
    for (int t = 0; t < CS; ++t) {
        us4 av = *(const us4*)&Ga[base + (size_t)t * Dd];
        us4 bv = *(const us4*)&Gb[base + (size_t)t * Dd];
        #pragma unroll
        for (int j = 0; j < 4; ++j) {
            float aa = bf2f(av[j]);
            float bb = bf2f(bv[j]);
            p[j] *= aa;
            h[j] = aa * h[j] + bb;
        }
    }
    size_t o = ((size_t)b * CH + c) * Dd + tid * 4;
    *(float4*)&P[o]    = make_float4(p[0], p[1], p[2], p[3]);
    *(float4*)&Hend[o] = make_float4(h[0], h[1], h[2], h[3]);
}

// 64-thread blocks: spread the 4096 serial carry chains over 64 CUs.
__global__ __launch_bounds__(64) void scan_pass2(
    const float* __restrict__ P, const float* __restrict__ Hend,
    const float* __restrict__ h0, float* __restrict__ Carry)
{
    int idx = blockIdx.x * 64 + threadIdx.x;  // B*D = 4096
    int b = idx / Dd, d = idx % Dd;
    float carry = h0[d];
    for (int c = 0; c < CH; ++c) {
        size_t o = ((size_t)b * CH + c) * Dd + d;
        Carry[o] = carry;
        carry = P[o] * carry + Hend[o];
    }
}

// Replay with carry + fused ogate/residual + fused RMSNorm2.
// 512 threads / 2 chunks per block; software-pipelined reduction:
// ONE __syncthreads per step (read red[t&1], pre-write red[(t+1)&1]).
__global__ __launch_bounds__(512) void scan_pass3_norm(
    const ushort* __restrict__ Ga, const ushort* __restrict__ Gb,
    const ushort* __restrict__ Gog, const float* __restrict__ Carry,
    const float* __restrict__ x, const float* __restrict__ norm2w,
    float* __restrict__ x1, ushort* __restrict__ xnb)
{
    int tid = threadIdx.x;
    int half = tid >> 8, ltid = tid & 255;
    int c = blockIdx.x * 2 + half, b = blockIdx.y;
    size_t base = ((size_t)b * Ll + (size_t)c * CS) * Dd + ltid * 4;
    float4 h4 = *(const float4*)&Carry[((size_t)b * CH + c) * Dd + ltid * 4];
    float h[4] = {h4.x, h4.y, h4.z, h4.w};
    float4 w4 = ((const float4*)norm2w)[ltid];
    float wv[4] = {w4.x, w4.y, w4.z, w4.w};
    __shared__ float red[2][2][4];    // [parity][half][wave-of-half]

    float v[4];
    // ---- prologue: step 0 ----
    {
        us4 av = *(const us4*)&Ga[base];
        us4 bv = *(const us4*)&Gb[base];
        us4 gv = *(const us4*)&Gog[base];
        float4 xv = *(const float4*)&x[base];
        float xs[4] = {xv.x, xv.y, xv.z, xv.w};
        #pragma unroll
        for (int j = 0; j < 4; ++j) {
            float aa = bf2f(av[j]);
            float bb = bf2f(bv[j]);
            h[j] = aa * h[j] + bb;
            v[j] = fast_tanh(h[j]) * bf2f(gv[j]) + xs[j];
        }
        *(float4*)&x1[base] = make_float4(v[0], v[1], v[2], v[3]);
        float ss = v[0]*v[0] + v[1]*v[1] + v[2]*v[2] + v[3]*v[3];
        #pragma unroll
        for (int off = 32; off > 0; off >>= 1) ss += __shfl_down(ss, off, 64);
        if ((ltid & 63) == 0) red[0][half][ltid >> 6] = ss;
    }
    __syncthreads();

    for (int t = 0; t < CS; ++t) {
        int p = t & 1;
        float scale = rsqrtf((red[p][half][0] + red[p][half][1] +
                              red[p][half][2] + red[p][half][3]) * (1.0f / Dd) + EPS);
        us4 ov;
        #pragma unroll
        for (int j = 0; j < 4; ++j) ov[j] = f2bf(v[j] * scale * wv[j]);
        *(us4*)&xnb[base + (size_t)t * Dd] = ov;

        if (t + 1 < CS) {
            size_t i = base + (size_t)(t + 1) * Dd;
            us4 av = *(const us4*)&Ga[i];
            us4 bv = *(const us4*)&Gb[i];
            us4 gv = *(const us4*)&Gog[i];
            float4 xv = *(const float4*)&x[i];
            float xs[4] = {xv.x, xv.y, xv.z, xv.w};
            #pragma unroll
            for (int j = 0; j < 4; ++j) {
                float aa = bf2f(av[j]);
                float bb = bf2f(bv[j]);
                h[j] = aa * h[j] + bb;
                v[j] = fast_tanh(h[j]) * bf2f(gv[j]) + xs[j];
            }
            *(float4*)&x1[i] = make_float4(v[0], v[1], v[2], v[3]);
            float ss = v[0]*v[0] + v[1]*v[1] + v[2]*v[2] + v[3]*v[3];
            #pragma unroll
            for (int off = 32; off > 0; off >>= 1) ss += __shfl_down(ss, off, 64);
            if ((ltid & 63) == 0) red[(t + 1) & 1][half][ltid >> 6] = ss;
        }
        __syncthreads();
    }
}

// ---------------------------------------------------------------------------
// Launch. Workspace (195 MB):
//   [0,4)   MB: W1t gates bf16 [2048,1024]   (input | forget)
//   [4,8)   MB: W2t gates bf16 [2048,1024]   (igate | ogate)
//   [8,16)  MB: wtFC   [16,24) MB: wtFCA   [24,32) MB: wtOUT
//   [32,64) MB: xnb bf16 [M,1024]
//   [64,192)MB: Ga/Gb/Gog bf16 (32MB each) -> later hff bf16 [M,4096]
//   [192,195)MB: P, Hend, Carry fp32
// d_out doubles as x1 then final out.
// ---------------------------------------------------------------------------
extern "C" void kernel_launch(void* const* d_in, const int* in_sizes, int n_in,
                              void* d_out, int out_size, void* d_ws, size_t ws_size,
                              hipStream_t stream)
{
    const float* x        = (const float*)d_in[0];
    const float* w_forget = (const float*)d_in[1];
    const float* b_forget = (const float*)d_in[2];
    const float* w_input  = (const float*)d_in[3];
    const float* b_input  = (const float*)d_in[4];
    const float* w_igate  = (const float*)d_in[5];
    const float* b_igate  = (const float*)d_in[6];
    const float* w_ogate  = (const float*)d_in[7];
    const float* b_ogate  = (const float*)d_in[8];
    const float* h0       = (const float*)d_in[9];
    const float* norm1_w  = (const float*)d_in[10];
    const float* norm2_w  = (const float*)d_in[11];
    const float* w_fc     = (const float*)d_in[12];
    const float* b_fc     = (const float*)d_in[13];
    const float* w_fc_act = (const float*)d_in[14];
    const float* b_fc_act = (const float*)d_in[15];
    const float* w_out    = (const float*)d_in[16];
    const float* b_out    = (const float*)d_in[17];
    float* out = (float*)d_out;   // x1, then final out

    char* ws = (char*)d_ws;
    const size_t MB = 1ull << 20;
    ushort* wtG1  = (ushort*)(ws + 0 * MB);
    ushort* wtG2  = (ushort*)(ws + 4 * MB);
    ushort* wtFC  = (ushort*)(ws + 8 * MB);
    ushort* wtFCA = (ushort*)(ws + 16 * MB);
    ushort* wtOUT = (ushort*)(ws + 24 * MB);
    ushort* xnb   = (ushort*)(ws + 32 * MB);
    ushort* Ga    = (ushort*)(ws + 64 * MB);
    ushort* Gb    = (ushort*)(ws + 96 * MB);
    ushort* Gog   = (ushort*)(ws + 128 * MB);
    ushort* hff   = (ushort*)(ws + 64 * MB);   // [M,4096] bf16, reuses gate region
    float*  P     = (float*)(ws + 192 * MB);
    float*  Hend  = (float*)(ws + 193 * MB);
    float*  Carry = (float*)(ws + 194 * MB);

    // 0) weights -> bf16 [N,K]
    transpose_cast_gates<<<dim3(32, 32, 4), 256, 0, stream>>>(
        w_input, w_forget, w_igate, w_ogate, wtG1, wtG2);
    transpose_cast_kernel<<<dim3(DFF/32, Dd/32), 256, 0, stream>>>(w_fc,     wtFC,  Dd, DFF);
    transpose_cast_kernel<<<dim3(DFF/32, Dd/32), 256, 0, stream>>>(w_fc_act, wtFCA, Dd, DFF);
    transpose_cast_kernel<<<dim3(Dd/32, DFF/32), 256, 0, stream>>>(w_out,    wtOUT, DFF, Dd);

    // 1) xn = rmsnorm(x) -> bf16  (wave-per-row, 4 rows/block)
    rmsnorm_bf16_kernel<<<Mm / 4, 256, 0, stream>>>(x, norm1_w, xnb);

    // 2) all four gates in one dual-GEMM (N = 2048), 256x128 tiles, 2-phase
    mfma_gemm_gates<<<(2048/128) * (Mm/256), 512, 0, stream>>>(
        xnb, wtG1, wtG2, b_input, b_forget, b_igate, b_ogate, Ga, Gb, Gog);

    // 3) chunked scan + fused ogate/residual + fused rmsnorm2
    dim3 sg(CH, Bb);
    scan_pass1<<<sg, 256, 0, stream>>>(Ga, Gb, P, Hend);
    scan_pass2<<<(Bb * Dd) / 64, 64, 0, stream>>>(P, Hend, h0, Carry);
    scan_pass3_norm<<<dim3(CH / 2, Bb), 512, 0, stream>>>(
        Ga, Gb, Gog, Carry, x, norm2_w, out, xnb);

    // 4) hff = (xn2@w_fc + b) * silu(xn2@w_fc_act + b)  -> bf16 [M,4096]
    mfma_gemm_swiglu<<<(DFF/128) * (Mm/256), 512, 0, stream>>>(
        xnb, wtFC, b_fc, wtFCA, b_fc_act, hff);

    // 5) out = hff @ w_out + b_out + x1   (in-place on d_out)
    mfma_gemm_residual<<<(Dd/256) * (Mm/256), 512, 0, stream>>>(
        hff, wtOUT, b_out, out);
}

// Round 10
// 859.843 us; speedup vs baseline: 1.0313x; 1.0069x over previous
//
#include <hip/hip_runtime.h>
#include <math.h>
#include <stdint.h>

// Problem dims (fixed by reference)
static constexpr int Bb  = 4;
static constexpr int Ll  = 4096;
static constexpr int Dd  = 1024;
static constexpr int DFF = 4096;
static constexpr int Mm  = Bb * Ll;     // 16384 rows
static constexpr int CH  = 64;          // scan chunks
static constexpr int CS  = Ll / CH;     // 64 steps per chunk
static constexpr float EPS = 1e-6f;

typedef __attribute__((ext_vector_type(8))) short short8;     // 8 bf16 (4 VGPRs)
typedef __attribute__((ext_vector_type(4))) float floatx4;    // MFMA C/D
typedef __attribute__((ext_vector_type(4))) unsigned short us4;

__device__ __forceinline__ float sigmoidf_(float v) { return 1.0f / (1.0f + __expf(-v)); }
// safe at +-inf: 2*sigmoid(2x)-1
__device__ __forceinline__ float fast_tanh(float x) {
    return 2.0f / (1.0f + __expf(-2.0f * x)) - 1.0f;
}
__device__ __forceinline__ ushort f2bf(float f) {
    union { float f; uint32_t u; } v; v.f = f;
    return (ushort)((v.u + 0x7FFFu + ((v.u >> 16) & 1u)) >> 16);   // RNE
}
__device__ __forceinline__ float bf2f(ushort h) {
    union { uint32_t u; float f; } v; v.u = (uint32_t)h << 16; return v.f;
}

// async global->LDS, 16 bytes per lane (wave-uniform base + lane*16 layout)
__device__ __forceinline__ void gload16(const ushort* g, ushort* l) {
    __builtin_amdgcn_global_load_lds(
        (const __attribute__((address_space(1))) uint32_t*)g,
        (__attribute__((address_space(3))) uint32_t*)l, 16, 0, 0);
}

// ===========================================================================
// 8-phase pipelined dual-GEMM core (R1-sub, session-best: swiglu 298 us,
// total 853.8, 0 bank conflicts).  512 thr / 8 waves, BK=64 split kk0/kk1.
//   Session A/B record: pinned-8ph swiglu 298 < 2ph 300/301 < unpinned-8ph
//   313; totals favor 8ph by 12-20 us (gates NT=16 benefits from finer
//   phases).  CLOSE_BAR = sched_barrier(0)+s_barrier after each MFMA
//   cluster (removing it HURT: R2->R3 298->313).
//   LDS buffer = [Akk0|Akk1|Bkk0|Bkk1], half-tile 256x32 bf16 (16 KB,
//   linear for global_load_lds); 2 buffers = 128 KB.
//   Swizzle (0-conflict proven): chunk (m,s) holds k-block s ^ ((m>>1)&3);
//   read slot = q ^ ((fr>>1)&3).
//   Per K-tile: 4 phases {ds_read 8/4 + stage 1 half-tile -> barrier ->
//   setprio(1) 16 MFMA setprio(0) -> [vmcnt(4) on ph1/ph3] -> CLOSE_BAR}.
//   vmcnt never drains to 0 mid-loop.  In-flight invariant: entering
//   K-tile t exactly {A(t,kk1),B(t,kk1)} (4 loads) outstanding; each
//   vmcnt(4) retires exactly the 2 half-tiles the next 2 phases read.
//   Race-safety: buffer overwrite happens >= 2 barriers after last read.
// ===========================================================================
static constexpr int HT_US  = 256 * 32;       // ushorts per half-tile (16 KB)
static constexpr int BUF_US = 4 * HT_US;      // per buffer (64 KB)

__device__ __forceinline__ void gemm_core_8ph(
    const ushort* __restrict__ A, const ushort* __restrict__ B1,
    const ushort* __restrict__ B2, int m0, int n0b1, int n0b2, int K,
    ushort* lds, floatx4 (&acc1)[8][2], floatx4 (&acc2)[8][2])
{
    const int tid = threadIdx.x;
    const int mm = tid >> 2, ss = tid & 3;
    const int kb = ss ^ ((mm >> 1) & 3);          // swizzled k-slot (staging)
    const ushort* pA0 = A  + (size_t)(m0 + mm) * K + kb * 8;
    const ushort* pA1 = pA0 + (size_t)128 * K;
    const ushort* pB0 = B1 + (size_t)(n0b1 + mm) * K + kb * 8;
    const ushort* pB1 = B2 + (size_t)(n0b2 + mm) * K + kb * 8;

    const int wave = tid >> 6, lane = tid & 63;
    const int wr = wave >> 2, wc = wave & 3;      // 2M x 4N wave grid
    const int fr = lane & 15, q = lane >> 4;
    const int slot8 = (q ^ ((fr >> 1) & 3)) << 3;
    const int aoff  = (wr * 128 + fr) * 32 + slot8;             // + mi*512
    const int boff  = 2 * HT_US + (wc * 32 + fr) * 32 + slot8;  // + ni*512 (+4096 side2)

    const int NT = K >> 6;

#define STG_A(bsel, kk, tt) do { \
        ushort* d_ = lds + (bsel) * BUF_US + (kk) * HT_US; \
        int o_ = (tt) * 64 + (kk) * 32; \
        gload16(pA0 + o_, d_ + tid * 8); \
        gload16(pA1 + o_, d_ + (tid + 512) * 8); } while (0)
#define STG_B(bsel, kk, tt) do { \
        ushort* d_ = lds + (bsel) * BUF_US + (2 + (kk)) * HT_US; \
        int o_ = (tt) * 64 + (kk) * 32; \
        gload16(pB0 + o_, d_ + tid * 8); \
        gload16(pB1 + o_, d_ + (tid + 512) * 8); } while (0)
#define MFMA_HALF(mh) do { \
        __builtin_amdgcn_s_setprio(1); \
        _Pragma("unroll") \
        for (int i_ = 0; i_ < 4; ++i_) { \
            acc1[(mh)*4+i_][0] = __builtin_amdgcn_mfma_f32_16x16x32_bf16(a[i_], b[0], acc1[(mh)*4+i_][0], 0, 0, 0); \
            acc2[(mh)*4+i_][0] = __builtin_amdgcn_mfma_f32_16x16x32_bf16(a[i_], c[0], acc2[(mh)*4+i_][0], 0, 0, 0); \
            acc1[(mh)*4+i_][1] = __builtin_amdgcn_mfma_f32_16x16x32_bf16(a[i_], b[1], acc1[(mh)*4+i_][1], 0, 0, 0); \
            acc2[(mh)*4+i_][1] = __builtin_amdgcn_mfma_f32_16x16x32_bf16(a[i_], c[1], acc2[(mh)*4+i_][1], 0, 0, 0); \
        } \
        __builtin_amdgcn_s_setprio(0); } while (0)
#define CLOSE_BAR() do { __builtin_amdgcn_sched_barrier(0); __builtin_amdgcn_s_barrier(); } while (0)

    // ---- prologue: stage K-tile 0; leave its kk1 halves in flight ----
    STG_A(0, 0, 0); STG_B(0, 0, 0); STG_A(0, 1, 0); STG_B(0, 1, 0);
    asm volatile("s_waitcnt vmcnt(4)" ::: "memory");
    CLOSE_BAR();

    for (int t = 0; t < NT; ++t) {
        const int buf = t & 1, nbuf = buf ^ 1;
        const bool pf = (t + 1 < NT);
        const ushort* Ab = lds + buf * BUF_US;
        short8 a[4], b[2], c[2];

        // ---------- phase 0: kk0, rows mh0 (8 ds_read + stage A kk0) ----------
        #pragma unroll
        for (int i = 0; i < 4; ++i) a[i] = *(const short8*)&Ab[aoff + i * 512];
        #pragma unroll
        for (int n = 0; n < 2; ++n) {
            b[n] = *(const short8*)&Ab[boff + n * 512];
            c[n] = *(const short8*)&Ab[boff + 4096 + n * 512];
        }
        if (pf) STG_A(nbuf, 0, t + 1);
        __builtin_amdgcn_s_barrier();
        MFMA_HALF(0);
        CLOSE_BAR();

        // ---------- phase 1: kk0, rows mh1 (4 ds_read + stage B kk0) ----------
        #pragma unroll
        for (int i = 0; i < 4; ++i) a[i] = *(const short8*)&Ab[aoff + (i + 4) * 512];
        if (pf) STG_B(nbuf, 0, t + 1);
        __builtin_amdgcn_s_barrier();
        MFMA_HALF(1);
        if (pf) asm volatile("s_waitcnt vmcnt(4)" ::: "memory");
        else    asm volatile("s_waitcnt vmcnt(0)" ::: "memory");
        CLOSE_BAR();

        // ---------- phase 2: kk1, rows mh0 (8 ds_read + stage A kk1) ----------
        const ushort* Ab1 = Ab + HT_US;
        #pragma unroll
        for (int i = 0; i < 4; ++i) a[i] = *(const short8*)&Ab1[aoff + i * 512];
        #pragma unroll
        for (int n = 0; n < 2; ++n) {
            b[n] = *(const short8*)&Ab1[boff + n * 512];
            c[n] = *(const short8*)&Ab1[boff + 4096 + n * 512];
        }
        if (pf) STG_A(nbuf, 1, t + 1);
        __builtin_amdgcn_s_barrier();
        MFMA_HALF(0);
        CLOSE_BAR();

        // ---------- phase 3: kk1, rows mh1 (4 ds_read + stage B kk1) ----------
        #pragma unroll
        for (int i = 0; i < 4; ++i) a[i] = *(const short8*)&Ab1[aoff + (i + 4) * 512];
        if (pf) STG_B(nbuf, 1, t + 1);
        __builtin_amdgcn_s_barrier();
        MFMA_HALF(1);
        if (pf) asm volatile("s_waitcnt vmcnt(4)" ::: "memory");
        CLOSE_BAR();
    }
#undef STG_A
#undef STG_B
#undef MFMA_HALF
#undef CLOSE_BAR
}

// ---------------------------------------------------------------------------
// Fused QuasiLSTM gate GEMM (dual, shared A), N = 2048:
//   W1t rows [0,1024) = w_input^T,  [1024,2048) = w_forget^T
//   W2t rows [0,1024) = w_igate^T,  [1024,2048) = w_ogate^T
// col <  1024:  Gb  = tanh(z1) * sigmoid(z2)
// col >= 1024:  Ga  = sigmoid(z1);  Gog = sigmoid(z2)
// ---------------------------------------------------------------------------
__global__ __launch_bounds__(512) void mfma_gemm_gates(
    const ushort* __restrict__ A, const ushort* __restrict__ W1t,
    const ushort* __restrict__ W2t,
    const float* __restrict__ b_input, const float* __restrict__ b_forget,
    const float* __restrict__ b_igate, const float* __restrict__ b_ogate,
    ushort* __restrict__ Ga, ushort* __restrict__ Gb, ushort* __restrict__ Gog)
{
    __shared__ __align__(16) ushort lds[2 * BUF_US];
    // XCD-slice swizzle: each XCD owns 2 bx columns (B-slice 1MB, L2-resident)
    int xcd = blockIdx.x & 7, i = blockIdx.x >> 3;   // i in [0,128)
    int bx = xcd * 2 + (i & 1), by = i >> 1;
    int m0 = by * 256, n0 = bx * 128;

    floatx4 acc1[8][2] = {};
    floatx4 acc2[8][2] = {};
    gemm_core_8ph(A, W1t, W2t, m0, n0, n0, Dd, lds, acc1, acc2);

    int tid = threadIdx.x, wave = tid >> 6, lane = tid & 63;
    int wr = wave >> 2, wc = wave & 3, fr = lane & 15, q = lane >> 4;
    #pragma unroll
    for (int ni = 0; ni < 2; ++ni) {
        int col = n0 + wc * 32 + ni * 16 + fr;        // [0,2048)
        if (col < 1024) {
            float b1v = b_input[col], b2v = b_igate[col];
            #pragma unroll
            for (int mi = 0; mi < 8; ++mi)
                #pragma unroll
                for (int r = 0; r < 4; ++r) {
                    int row = m0 + wr * 128 + mi * 16 + q * 4 + r;
                    float z1 = acc1[mi][ni][r] + b1v;
                    float z2 = acc2[mi][ni][r] + b2v;
                    Gb[(size_t)row * Dd + col] = f2bf(fast_tanh(z1) * sigmoidf_(z2));
                }
        } else {
            int c2 = col - 1024;
            float b1v = b_forget[c2], b2v = b_ogate[c2];
            #pragma unroll
            for (int mi = 0; mi < 8; ++mi)
                #pragma unroll
                for (int r = 0; r < 4; ++r) {
                    int row = m0 + wr * 128 + mi * 16 + q * 4 + r;
                    float z1 = acc1[mi][ni][r] + b1v;
                    float z2 = acc2[mi][ni][r] + b2v;
                    Ga[(size_t)row * Dd + c2]  = f2bf(sigmoidf_(z1));
                    Gog[(size_t)row * Dd + c2] = f2bf(sigmoidf_(z2));
                }
        }
    }
}

// ---------------------------------------------------------------------------
// MFMA dual GEMM for SwiGLU: C = (A@W1+b1) * silu(A@W2+b2), bf16 out
// ---------------------------------------------------------------------------
__global__ __launch_bounds__(512) void mfma_gemm_swiglu(
    const ushort* __restrict__ A, const ushort* __restrict__ W1t,
    const float* __restrict__ b1, const ushort* __restrict__ W2t,
    const float* __restrict__ b2, ushort* __restrict__ C)
{
    __shared__ __align__(16) ushort lds[2 * BUF_US];
    // XCD-slice swizzle: each XCD owns 4 bx columns (B-slice 2MB, L2-resident)
    int xcd = blockIdx.x & 7, i = blockIdx.x >> 3;   // i in [0,256)
    int bx = xcd * 4 + (i & 3), by = i >> 2;
    int m0 = by * 256, n0 = bx * 128;

    floatx4 acc1[8][2] = {};
    floatx4 acc2[8][2] = {};
    gemm_core_8ph(A, W1t, W2t, m0, n0, n0, Dd, lds, acc1, acc2);

    int tid = threadIdx.x, wave = tid >> 6, lane = tid & 63;
    int wr = wave >> 2, wc = wave & 3, fr = lane & 15, q = lane >> 4;
    #pragma unroll
    for (int ni = 0; ni < 2; ++ni) {
        int col = n0 + wc * 32 + ni * 16 + fr;
        float b1v = b1[col], b2v = b2[col];
        #pragma unroll
        for (int mi = 0; mi < 8; ++mi)
            #pragma unroll
            for (int r = 0; r < 4; ++r) {
                int row = m0 + wr * 128 + mi * 16 + q * 4 + r;
                float z1 = acc1[mi][ni][r] + b1v;
                float z2 = acc2[mi][ni][r] + b2v;
                C[(size_t)row * DFF + col] = f2bf(z1 * z2 * sigmoidf_(z2));
            }
    }
}

// ---------------------------------------------------------------------------
// MFMA residual GEMM: out_f32 = A_bf16[M,K] @ Wt[N,K]^T + bias + R (R == out)
// Single-B: the 256-wide N tile is two 128 halves (acc1/acc2).
// ---------------------------------------------------------------------------
__global__ __launch_bounds__(512) void mfma_gemm_residual(
    const ushort* __restrict__ A, const ushort* __restrict__ Wt,
    const float* __restrict__ bias, float* __restrict__ C)
{
    __shared__ __align__(16) ushort lds[2 * BUF_US];
    int xcd = blockIdx.x & 7, i = blockIdx.x >> 3;   // i in [0,32)
    int s = xcd * 32 + i;
    int bx = s & 3, by = s >> 2;                     // bx fast: A-panel reuse
    int m0 = by * 256, n0 = bx * 256;

    floatx4 acc1[8][2] = {};
    floatx4 acc2[8][2] = {};
    gemm_core_8ph(A, Wt, Wt, m0, n0, n0 + 128, DFF, lds, acc1, acc2);

    int tid = threadIdx.x, wave = tid >> 6, lane = tid & 63;
    int wr = wave >> 2, wc = wave & 3, fr = lane & 15, q = lane >> 4;
    #pragma unroll
    for (int ni = 0; ni < 2; ++ni) {
        int col1 = n0 + wc * 32 + ni * 16 + fr;
        int col2 = col1 + 128;
        float bs1 = bias[col1], bs2 = bias[col2];
        #pragma unroll
        for (int mi = 0; mi < 8; ++mi)
            #pragma unroll
            for (int r = 0; r < 4; ++r) {
                int row = m0 + wr * 128 + mi * 16 + q * 4 + r;
                size_t i1 = (size_t)row * Dd + col1;
                size_t i2 = (size_t)row * Dd + col2;
                C[i1] = acc1[mi][ni][r] + bs1 + C[i1];  // same-thread RMW
                C[i2] = acc2[mi][ni][r] + bs2 + C[i2];
            }
    }
}

// ---------------------------------------------------------------------------
// Weight cast+transpose: W fp32 [K,N] -> Wt bf16 [N,K]
// ---------------------------------------------------------------------------
__global__ __launch_bounds__(256) void transpose_cast_kernel(
    const float* __restrict__ W, ushort* __restrict__ Wt, int K, int N)
{
    __shared__ float t[32][33];
    int lx = threadIdx.x & 31, ly = threadIdx.x >> 5;   // 32 x 8
    int n = blockIdx.x * 32 + lx;
    #pragma unroll
    for (int i = 0; i < 4; ++i) {
        int k = blockIdx.y * 32 + ly + i * 8;
        t[ly + i * 8][lx] = W[(size_t)k * N + n];
    }
    __syncthreads();
    int k2 = blockIdx.y * 32 + lx;
    #pragma unroll
    for (int i = 0; i < 4; ++i) {
        int n2 = blockIdx.x * 32 + ly + i * 8;
        Wt[(size_t)n2 * K + k2] = f2bf(t[lx][ly + i * 8]);
    }
}

// Batched: the two Dd x DFF FFN weights in one launch (grid.z picks source).
__global__ __launch_bounds__(256) void transpose_cast_ffn(
    const float* __restrict__ w_fc, const float* __restrict__ w_fc_act,
    ushort* __restrict__ wtFC, ushort* __restrict__ wtFCA)
{
    const float* W = blockIdx.z ? w_fc_act : w_fc;
    ushort* Wt = blockIdx.z ? wtFCA : wtFC;
    __shared__ float t[32][33];
    int lx = threadIdx.x & 31, ly = threadIdx.x >> 5;
    int n = blockIdx.x * 32 + lx;
    #pragma unroll
    for (int i = 0; i < 4; ++i) {
        int k = blockIdx.y * 32 + ly + i * 8;
        t[ly + i * 8][lx] = W[(size_t)k * DFF + n];
    }
    __syncthreads();
    int k2 = blockIdx.y * 32 + lx;
    #pragma unroll
    for (int i = 0; i < 4; ++i) {
        int n2 = blockIdx.x * 32 + ly + i * 8;
        Wt[(size_t)n2 * Dd + k2] = f2bf(t[lx][ly + i * 8]);
    }
}

// Batched version for the four 1024x1024 gate weights (grid.z picks source).
__global__ __launch_bounds__(256) void transpose_cast_gates(
    const float* __restrict__ w_i, const float* __restrict__ w_f,
    const float* __restrict__ w_g, const float* __restrict__ w_o,
    ushort* __restrict__ W1t, ushort* __restrict__ W2t)
{
    int z = blockIdx.z;
    const float* W = (z == 0) ? w_i : (z == 1) ? w_f : (z == 2) ? w_g : w_o;
    ushort* Wt = (z == 0) ? W1t : (z == 1) ? W1t + (size_t)1024 * Dd
               : (z == 2) ? W2t : W2t + (size_t)1024 * Dd;
    __shared__ float t[32][33];
    int lx = threadIdx.x & 31, ly = threadIdx.x >> 5;
    int n = blockIdx.x * 32 + lx;
    #pragma unroll
    for (int i = 0; i < 4; ++i) {
        int k = blockIdx.y * 32 + ly + i * 8;
        t[ly + i * 8][lx] = W[(size_t)k * Dd + n];
    }
    __syncthreads();
    int k2 = blockIdx.y * 32 + lx;
    #pragma unroll
    for (int i = 0; i < 4; ++i) {
        int n2 = blockIdx.x * 32 + ly + i * 8;
        Wt[(size_t)n2 * Dd + k2] = f2bf(t[lx][ly + i * 8]);
    }
}

// ---------------------------------------------------------------------------
// RMSNorm fp32 in -> bf16 out.  One WAVE per row (4 rows/block):
// pure shfl_xor reduce — no LDS, no __syncthreads.
// ---------------------------------------------------------------------------
__global__ __launch_bounds__(256) void rmsnorm_bf16_kernel(
    const float* __restrict__ x, const float* __restrict__ w,
    ushort* __restrict__ o)
{
    int wave = threadIdx.x >> 6, lane = threadIdx.x & 63;
    int row = blockIdx.x * 4 + wave;
    const float4* xr = (const float4*)(x + (size_t)row * Dd);
    float4 v[4];
    float ss = 0.f;
    #pragma unroll
    for (int j = 0; j < 4; ++j) {
        v[j] = xr[lane + j * 64];
        ss += v[j].x * v[j].x + v[j].y * v[j].y + v[j].z * v[j].z + v[j].w * v[j].w;
    }
    #pragma unroll
    for (int off = 1; off < 64; off <<= 1) ss += __shfl_xor(ss, off, 64);
    float scale = rsqrtf(ss * (1.0f / Dd) + EPS);
    #pragma unroll
    for (int j = 0; j < 4; ++j) {
        float4 wv = ((const float4*)w)[lane + j * 64];
        us4 ov;
        ov.x = f2bf(v[j].x * scale * wv.x);
        ov.y = f2bf(v[j].y * scale * wv.y);
        ov.z = f2bf(v[j].z * scale * wv.z);
        ov.w = f2bf(v[j].w * scale * wv.w);
        *(us4*)&o[(size_t)row * Dd + (lane + j * 64) * 4] = ov;
    }
}

// ---------------------------------------------------------------------------
// Chunked linear recurrence, 4 channels/thread (ushort4 loads)
// ---------------------------------------------------------------------------
__global__ __launch_bounds__(256) void scan_pass1(
    const ushort* __restrict__ Ga, const ushort* __restrict__ Gb,
    float* __restrict__ P, float* __restrict__ Hend)
{
    int tid = threadIdx.x;
    int c = blockIdx.x, b = blockIdx.y;
    size_t base = ((size_t)b * Ll + (size_t)c * CS) * Dd + tid * 4;
    float p[4] = {1.f, 1.f, 1.f, 1.f};
    float h[4] = {};
    #pragma unroll 4
    for (int t = 0; t < CS; ++t) {
        us4 av = *(const us4*)&Ga[base + (size_t)t * Dd];
        us4 bv = *(const us4*)&Gb[base + (size_t)t * Dd];
        #pragma unroll
        for (int j = 0; j < 4; ++j) {
            float aa = bf2f(av[j]);
            float bb = bf2f(bv[j]);
            p[j] *= aa;
            h[j] = aa * h[j] + bb;
        }
    }
    size_t o = ((size_t)b * CH + c) * Dd + tid * 4;
    *(float4*)&P[o]    = make_float4(p[0], p[1], p[2], p[3]);
    *(float4*)&Hend[o] = make_float4(h[0], h[1], h[2], h[3]);
}

// 64-thread blocks: spread the 4096 serial carry chains over 64 CUs.
__global__ __launch_bounds__(64) void scan_pass2(
    const float* __restrict__ P, const float* __restrict__ Hend,
    const float* __restrict__ h0, float* __restrict__ Carry)
{
    int idx = blockIdx.x * 64 + threadIdx.x;  // B*D = 4096
    int b = idx / Dd, d = idx % Dd;
    float carry = h0[d];
    for (int c = 0; c < CH; ++c) {
        size_t o = ((size_t)b * CH + c) * Dd + d;
        Carry[o] = carry;
        carry = P[o] * carry + Hend[o];
    }
}

// Replay with carry + fused ogate/residual + fused RMSNorm2.
// 512 threads / 2 chunks per block; software-pipelined reduction:
// ONE __syncthreads per step (read red[t&1], pre-write red[(t+1)&1]).
__global__ __launch_bounds__(512) void scan_pass3_norm(
    const ushort* __restrict__ Ga, const ushort* __restrict__ Gb,
    const ushort* __restrict__ Gog, const float* __restrict__ Carry,
    const float* __restrict__ x, const float* __restrict__ norm2w,
    float* __restrict__ x1, ushort* __restrict__ xnb)
{
    int tid = threadIdx.x;
    int half = tid >> 8, ltid = tid & 255;
    int c = blockIdx.x * 2 + half, b = blockIdx.y;
    size_t base = ((size_t)b * Ll + (size_t)c * CS) * Dd + ltid * 4;
    float4 h4 = *(const float4*)&Carry[((size_t)b * CH + c) * Dd + ltid * 4];
    float h[4] = {h4.x, h4.y, h4.z, h4.w};
    float4 w4 = ((const float4*)norm2w)[ltid];
    float wv[4] = {w4.x, w4.y, w4.z, w4.w};
    __shared__ float red[2][2][4];    // [parity][half][wave-of-half]

    float v[4];
    // ---- prologue: step 0 ----
    {
        us4 av = *(const us4*)&Ga[base];
        us4 bv = *(const us4*)&Gb[base];
        us4 gv = *(const us4*)&Gog[base];
        float4 xv = *(const float4*)&x[base];
        float xs[4] = {xv.x, xv.y, xv.z, xv.w};
        #pragma unroll
        for (int j = 0; j < 4; ++j) {
            float aa = bf2f(av[j]);
            float bb = bf2f(bv[j]);
            h[j] = aa * h[j] + bb;
            v[j] = fast_tanh(h[j]) * bf2f(gv[j]) + xs[j];
        }
        *(float4*)&x1[base] = make_float4(v[0], v[1], v[2], v[3]);
        float ss = v[0]*v[0] + v[1]*v[1] + v[2]*v[2] + v[3]*v[3];
        #pragma unroll
        for (int off = 32; off > 0; off >>= 1) ss += __shfl_down(ss, off, 64);
        if ((ltid & 63) == 0) red[0][half][ltid >> 6] = ss;
    }
    __syncthreads();

    for (int t = 0; t < CS; ++t) {
        int p = t & 1;
        float scale = rsqrtf((red[p][half][0] + red[p][half][1] +
                              red[p][half][2] + red[p][half][3]) * (1.0f / Dd) + EPS);
        us4 ov;
        #pragma unroll
        for (int j = 0; j < 4; ++j) ov[j] = f2bf(v[j] * scale * wv[j]);
        *(us4*)&xnb[base + (size_t)t * Dd] = ov;

        if (t + 1 < CS) {
            size_t i = base + (size_t)(t + 1) * Dd;
            us4 av = *(const us4*)&Ga[i];
            us4 bv = *(const us4*)&Gb[i];
            us4 gv = *(const us4*)&Gog[i];
            float4 xv = *(const float4*)&x[i];
            float xs[4] = {xv.x, xv.y, xv.z, xv.w};
            #pragma unroll
            for (int j = 0; j < 4; ++j) {
                float aa = bf2f(av[j]);
                float bb = bf2f(bv[j]);
                h[j] = aa * h[j] + bb;
                v[j] = fast_tanh(h[j]) * bf2f(gv[j]) + xs[j];
            }
            *(float4*)&x1[i] = make_float4(v[0], v[1], v[2], v[3]);
            float ss = v[0]*v[0] + v[1]*v[1] + v[2]*v[2] + v[3]*v[3];
            #pragma unroll
            for (int off = 32; off > 0; off >>= 1) ss += __shfl_down(ss, off, 64);
            if ((ltid & 63) == 0) red[(t + 1) & 1][half][ltid >> 6] = ss;
        }
        __syncthreads();
    }
}

// ---------------------------------------------------------------------------
// Launch. Workspace (195 MB):
//   [0,4)   MB: W1t gates bf16 [2048,1024]   (input | forget)
//   [4,8)   MB: W2t gates bf16 [2048,1024]   (igate | ogate)
//   [8,16)  MB: wtFC   [16,24) MB: wtFCA   [24,32) MB: wtOUT
//   [32,64) MB: xnb bf16 [M,1024]
//   [64,192)MB: Ga/Gb/Gog bf16 (32MB each) -> later hff bf16 [M,4096]
//   [192,195)MB: P, Hend, Carry fp32
// d_out doubles as x1 then final out.
// ---------------------------------------------------------------------------
extern "C" void kernel_launch(void* const* d_in, const int* in_sizes, int n_in,
                              void* d_out, int out_size, void* d_ws, size_t ws_size,
                              hipStream_t stream)
{
    const float* x        = (const float*)d_in[0];
    const float* w_forget = (const float*)d_in[1];
    const float* b_forget = (const float*)d_in[2];
    const float* w_input  = (const float*)d_in[3];
    const float* b_input  = (const float*)d_in[4];
    const float* w_igate  = (const float*)d_in[5];
    const float* b_igate  = (const float*)d_in[6];
    const float* w_ogate  = (const float*)d_in[7];
    const float* b_ogate  = (const float*)d_in[8];
    const float* h0       = (const float*)d_in[9];
    const float* norm1_w  = (const float*)d_in[10];
    const float* norm2_w  = (const float*)d_in[11];
    const float* w_fc     = (const float*)d_in[12];
    const float* b_fc     = (const float*)d_in[13];
    const float* w_fc_act = (const float*)d_in[14];
    const float* b_fc_act = (const float*)d_in[15];
    const float* w_out    = (const float*)d_in[16];
    const float* b_out    = (const float*)d_in[17];
    float* out = (float*)d_out;   // x1, then final out

    char* ws = (char*)d_ws;
    const size_t MB = 1ull << 20;
    ushort* wtG1  = (ushort*)(ws + 0 * MB);
    ushort* wtG2  = (ushort*)(ws + 4 * MB);
    ushort* wtFC  = (ushort*)(ws + 8 * MB);
    ushort* wtFCA = (ushort*)(ws + 16 * MB);
    ushort* wtOUT = (ushort*)(ws + 24 * MB);
    ushort* xnb   = (ushort*)(ws + 32 * MB);
    ushort* Ga    = (ushort*)(ws + 64 * MB);
    ushort* Gb    = (ushort*)(ws + 96 * MB);
    ushort* Gog   = (ushort*)(ws + 128 * MB);
    ushort* hff   = (ushort*)(ws + 64 * MB);   // [M,4096] bf16, reuses gate region
    float*  P     = (float*)(ws + 192 * MB);
    float*  Hend  = (float*)(ws + 193 * MB);
    float*  Carry = (float*)(ws + 194 * MB);

    // 0) weights -> bf16 [N,K]
    transpose_cast_gates<<<dim3(32, 32, 4), 256, 0, stream>>>(
        w_input, w_forget, w_igate, w_ogate, wtG1, wtG2);
    transpose_cast_ffn<<<dim3(DFF/32, Dd/32, 2), 256, 0, stream>>>(
        w_fc, w_fc_act, wtFC, wtFCA);
    transpose_cast_kernel<<<dim3(Dd/32, DFF/32), 256, 0, stream>>>(w_out, wtOUT, DFF, Dd);

    // 1) xn = rmsnorm(x) -> bf16  (wave-per-row, 4 rows/block)
    rmsnorm_bf16_kernel<<<Mm / 4, 256, 0, stream>>>(x, norm1_w, xnb);

    // 2) all four gates in one dual-GEMM (N = 2048), 256x128 tiles, 8-phase
    mfma_gemm_gates<<<(2048/128) * (Mm/256), 512, 0, stream>>>(
        xnb, wtG1, wtG2, b_input, b_forget, b_igate, b_ogate, Ga, Gb, Gog);

    // 3) chunked scan + fused ogate/residual + fused rmsnorm2
    dim3 sg(CH, Bb);
    scan_pass1<<<sg, 256, 0, stream>>>(Ga, Gb, P, Hend);
    scan_pass2<<<(Bb * Dd) / 64, 64, 0, stream>>>(P, Hend, h0, Carry);
    scan_pass3_norm<<<dim3(CH / 2, Bb), 512, 0, stream>>>(
        Ga, Gb, Gog, Carry, x, norm2_w, out, xnb);

    // 4) hff = (xn2@w_fc + b) * silu(xn2@w_fc_act + b)  -> bf16 [M,4096]
    mfma_gemm_swiglu<<<(DFF/128) * (Mm/256), 512, 0, stream>>>(
        xnb, wtFC, b_fc, wtFCA, b_fc_act, hff);

    // 5) out = hff @ w_out + b_out + x1   (in-place on d_out)
    mfma_gemm_residual<<<(Dd/256) * (Mm/256), 512, 0, stream>>>(
        hff, wtOUT, b_out, out);
}